// Round 1
// baseline (587.889 us; speedup 1.0000x reference)
//
#include <hip/hip_runtime.h>
#include <math.h>

#define NN 50000
#define NE 800000
#define FIN 128
#define C1 16
#define H1 4
#define FMID 64   // H1*C1
#define NC 10     // classes, conv2 channels
#define NEG 0.2f

// ---------------- helpers ----------------

__device__ __forceinline__ void atomicMaxF(float* addr, float val) {
    // init value is -inf; standard sign-split trick (no NaNs in this workload)
    if (val >= 0.f) {
        atomicMax((int*)addr, __float_as_int(val));
    } else {
        atomicMin((unsigned int*)addr, (unsigned int)__float_as_int(val));
    }
}

__device__ __forceinline__ float lrelu(float v) {
    return v > 0.f ? v : NEG * v;
}

// ---------------- init ----------------

// hacc=0 (NN*64), m1=-inf (NN*4), d1=0 (NN*4)
__global__ void k_init1(float* __restrict__ hacc, float* __restrict__ m1, float* __restrict__ d1) {
    int i = blockIdx.x * blockDim.x + threadIdx.x;
    const int nh = NN * 64, nm = NN * 4;
    if (i < nh) {
        hacc[i] = 0.f;
    } else if (i < nh + nm) {
        m1[i - nh] = -INFINITY;
    } else if (i < nh + 2 * nm) {
        d1[i - nh - nm] = 0.f;
    }
}

// out[n][c]=b2[c] (NN*NC), m2=-inf (NN), d2=0 (NN)
__global__ void k_init2(float* __restrict__ out, const float* __restrict__ b2,
                        float* __restrict__ m2, float* __restrict__ d2) {
    int i = blockIdx.x * blockDim.x + threadIdx.x;
    const int no = NN * NC;
    if (i < no) {
        out[i] = b2[i % NC];
    } else if (i < no + NN) {
        m2[i - no] = -INFINITY;
    } else if (i < no + 2 * NN) {
        d2[i - no - NN] = 0.f;
    }
}

// ---------------- layer 1 ----------------

// xl1 = x @ W1l, xr1 = x @ W1r   (one block per node, 128 threads)
__global__ __launch_bounds__(128) void k_gemm1(const float* __restrict__ x,
                                               const float* __restrict__ Wl,
                                               const float* __restrict__ Wr,
                                               float* __restrict__ xl,
                                               float* __restrict__ xr) {
    __shared__ float xs[FIN];
    const int n = blockIdx.x;
    const int t = threadIdx.x;
    xs[t] = x[(size_t)n * FIN + t];
    __syncthreads();
    const float* __restrict__ W = (t < 64) ? Wl : Wr;
    const int col = t & 63;
    float acc = 0.f;
#pragma unroll 8
    for (int k = 0; k < FIN; ++k) acc = fmaf(xs[k], W[k * 64 + col], acc);
    if (t < 64) xl[(size_t)n * 64 + col] = acc;
    else        xr[(size_t)n * 64 + col] = acc;
}

// per (edge, head): logit + atomicMax into m1
__global__ void k_elogit1(const float* __restrict__ xl, const float* __restrict__ xr,
                          const int* __restrict__ ei, const float* __restrict__ att1,
                          float* __restrict__ logits, float* __restrict__ m1) {
    int tid = blockIdx.x * blockDim.x + threadIdx.x;
    if (tid >= NE * H1) return;
    const int e = tid >> 2, h = tid & 3;
    const int src = ei[e], dst = ei[NE + e];
    const float4* __restrict__ a  = (const float4*)(xl + (size_t)src * 64 + h * 16);
    const float4* __restrict__ b  = (const float4*)(xr + (size_t)dst * 64 + h * 16);
    const float4* __restrict__ at = (const float4*)(att1 + h * 16);
    float acc = 0.f;
#pragma unroll
    for (int q = 0; q < 4; ++q) {
        float4 va = a[q], vb = b[q], vt = at[q];
        acc = fmaf(lrelu(va.x + vb.x), vt.x, acc);
        acc = fmaf(lrelu(va.y + vb.y), vt.y, acc);
        acc = fmaf(lrelu(va.z + vb.z), vt.z, acc);
        acc = fmaf(lrelu(va.w + vb.w), vt.w, acc);
    }
    logits[tid] = acc;
    atomicMaxF(&m1[dst * 4 + h], acc);
}

// per (edge, head): ex = exp(logit - m1[dst]); atomicAdd denom
__global__ void k_exp1(const int* __restrict__ ei, float* __restrict__ logits,
                       const float* __restrict__ m1, float* __restrict__ d1) {
    int tid = blockIdx.x * blockDim.x + threadIdx.x;
    if (tid >= NE * H1) return;
    const int e = tid >> 2, h = tid & 3;
    const int dst = ei[NE + e];
    float ex = expf(logits[tid] - m1[dst * 4 + h]);
    logits[tid] = ex;
    atomicAdd(&d1[dst * 4 + h], ex);
}

// per (edge, feature f of 64): hacc[dst][f] += alpha * xl[src][f]
__global__ void k_scat1(const int* __restrict__ ei, const float* __restrict__ ex,
                        const float* __restrict__ d1, const float* __restrict__ xl,
                        float* __restrict__ hacc) {
    long long tid = (long long)blockIdx.x * blockDim.x + threadIdx.x;
    if (tid >= (long long)NE * 64) return;
    const int e = (int)(tid >> 6);
    const int f = (int)(tid & 63);
    const int h = f >> 4;
    const int src = ei[e], dst = ei[NE + e];
    const float alpha = ex[e * 4 + h] / d1[dst * 4 + h];
    atomicAdd(&hacc[(size_t)dst * 64 + f], alpha * xl[(size_t)src * 64 + f]);
}

// h = elu(hacc + b1)
__global__ void k_elu(float* __restrict__ hacc, const float* __restrict__ b1) {
    int i = blockIdx.x * blockDim.x + threadIdx.x;
    if (i >= NN * 64) return;
    const float v = hacc[i] + b1[i & 63];
    hacc[i] = v > 0.f ? v : expm1f(v);
}

// ---------------- layer 2 ----------------

// xl2 = h @ W2l, xr2 = h @ W2r (one block per node, 64 threads; 20 active in compute)
__global__ __launch_bounds__(64) void k_gemm2(const float* __restrict__ h,
                                              const float* __restrict__ Wl,
                                              const float* __restrict__ Wr,
                                              float* __restrict__ xl2,
                                              float* __restrict__ xr2) {
    __shared__ float hs[FMID];
    const int n = blockIdx.x;
    const int t = threadIdx.x;
    hs[t] = h[(size_t)n * FMID + t];
    __syncthreads();
    const int lane = t & 31;
    if (lane < NC) {
        const float* __restrict__ W = (t < 32) ? Wl : Wr;
        float acc = 0.f;
#pragma unroll 8
        for (int k = 0; k < FMID; ++k) acc = fmaf(hs[k], W[k * NC + lane], acc);
        float* __restrict__ o = (t < 32) ? xl2 : xr2;
        o[(size_t)n * NC + lane] = acc;
    }
}

// per edge: logit2 + atomicMax m2
__global__ void k_elogit2(const float* __restrict__ xl2, const float* __restrict__ xr2,
                          const int* __restrict__ ei, const float* __restrict__ att2,
                          float* __restrict__ logits2, float* __restrict__ m2) {
    int e = blockIdx.x * blockDim.x + threadIdx.x;
    if (e >= NE) return;
    const int src = ei[e], dst = ei[NE + e];
    const float* __restrict__ a = xl2 + (size_t)src * NC;
    const float* __restrict__ b = xr2 + (size_t)dst * NC;
    float acc = 0.f;
#pragma unroll
    for (int c = 0; c < NC; ++c) acc = fmaf(lrelu(a[c] + b[c]), att2[c], acc);
    logits2[e] = acc;
    atomicMaxF(&m2[dst], acc);
}

// per edge: ex2 = exp(logit2 - m2[dst]); atomicAdd denom2
__global__ void k_exp2(const int* __restrict__ ei, float* __restrict__ logits2,
                       const float* __restrict__ m2, float* __restrict__ d2) {
    int e = blockIdx.x * blockDim.x + threadIdx.x;
    if (e >= NE) return;
    const int dst = ei[NE + e];
    float ex = expf(logits2[e] - m2[dst]);
    logits2[e] = ex;
    atomicAdd(&d2[dst], ex);
}

// per (edge, class): out[dst][c] += alpha * xl2[src][c]
__global__ void k_scat2(const int* __restrict__ ei, const float* __restrict__ ex2,
                        const float* __restrict__ d2, const float* __restrict__ xl2,
                        float* __restrict__ out) {
    int tid = blockIdx.x * blockDim.x + threadIdx.x;
    if (tid >= NE * NC) return;
    const int e = tid / NC;
    const int c = tid - e * NC;
    const int src = ei[e], dst = ei[NE + e];
    const float alpha = ex2[e] / d2[dst];
    atomicAdd(&out[(size_t)dst * NC + c], alpha * xl2[(size_t)src * NC + c]);
}

// ---------------- launch ----------------

extern "C" void kernel_launch(void* const* d_in, const int* in_sizes, int n_in,
                              void* d_out, int out_size, void* d_ws, size_t ws_size,
                              hipStream_t stream) {
    const float* x    = (const float*)d_in[0];
    const int*   ei   = (const int*)d_in[1];
    const float* W1l  = (const float*)d_in[2];
    const float* W1r  = (const float*)d_in[3];
    const float* att1 = (const float*)d_in[4];
    const float* b1   = (const float*)d_in[5];
    const float* W2l  = (const float*)d_in[6];
    const float* W2r  = (const float*)d_in[7];
    const float* att2 = (const float*)d_in[8];
    const float* b2   = (const float*)d_in[9];
    float* out = (float*)d_out;

    // workspace layout (floats)
    float* ws  = (float*)d_ws;
    float* xl1 = ws;                           // NN*64
    float* xr1 = xl1 + (size_t)NN * 64;        // NN*64
    float* ex1 = xr1 + (size_t)NN * 64;        // NE*4 (logits, then exp)
    float* m1  = ex1 + (size_t)NE * 4;         // NN*4
    float* d1  = m1  + (size_t)NN * 4;         // NN*4
    float* hb  = d1  + (size_t)NN * 4;         // NN*64 (hacc -> h)
    float* xl2 = hb  + (size_t)NN * 64;        // NN*NC
    float* xr2 = xl2 + (size_t)NN * NC;        // NN*NC
    float* ex2 = xr2 + (size_t)NN * NC;        // NE
    float* m2  = ex2 + (size_t)NE;             // NN
    float* d2  = m2  + (size_t)NN;             // NN

    const int B = 256;

    // init
    {
        int n1 = NN * 64 + NN * 8;
        k_init1<<<(n1 + B - 1) / B, B, 0, stream>>>(hb, m1, d1);
        int n2 = NN * NC + 2 * NN;
        k_init2<<<(n2 + B - 1) / B, B, 0, stream>>>(out, b2, m2, d2);
    }

    // layer 1
    k_gemm1<<<NN, 128, 0, stream>>>(x, W1l, W1r, xl1, xr1);
    {
        int n = NE * H1;
        k_elogit1<<<(n + B - 1) / B, B, 0, stream>>>(xl1, xr1, ei, att1, ex1, m1);
        k_exp1<<<(n + B - 1) / B, B, 0, stream>>>(ei, ex1, m1, d1);
    }
    {
        long long n = (long long)NE * 64;
        k_scat1<<<(unsigned)((n + B - 1) / B), B, 0, stream>>>(ei, ex1, d1, xl1, hb);
    }
    k_elu<<<(NN * 64 + B - 1) / B, B, 0, stream>>>(hb, b1);

    // layer 2
    k_gemm2<<<NN, 64, 0, stream>>>(hb, W2l, W2r, xl2, xr2);
    k_elogit2<<<(NE + B - 1) / B, B, 0, stream>>>(xl2, xr2, ei, att2, ex2, m2);
    k_exp2<<<(NE + B - 1) / B, B, 0, stream>>>(ei, ex2, m2, d2);
    k_scat2<<<(NE * NC + B - 1) / B, B, 0, stream>>>(ei, ex2, d2, xl2, out);
}

// Round 2
// 287.140 us; speedup vs baseline: 2.0474x; 2.0474x over previous
//
#include <hip/hip_runtime.h>
#include <math.h>

#define NN 50000
#define NE 800000
#define FIN 128
#define C1 16
#define H1 4
#define FMID 64   // H1*C1
#define NC 10     // classes, conv2 channels
#define NEG 0.2f

#define SCAN_B 256
#define NBLK ((NN + SCAN_B - 1) / SCAN_B)   // 196

__device__ __forceinline__ float lrelu(float v) {
    return v > 0.f ? v : NEG * v;
}

// ---------------- CSR build ----------------

__global__ void k_zero(int* __restrict__ deg) {
    int i = blockIdx.x * blockDim.x + threadIdx.x;
    if (i < NN) deg[i] = 0;
}

__global__ void k_count(const int* __restrict__ ei, int* __restrict__ deg) {
    int e = blockIdx.x * blockDim.x + threadIdx.x;
    if (e >= NE) return;
    atomicAdd(&deg[ei[NE + e]], 1);
}

// per-block exclusive scan of deg -> rowptr (local), block totals -> part
__global__ __launch_bounds__(SCAN_B) void k_scan1(const int* __restrict__ deg,
                                                  int* __restrict__ rowptr,
                                                  int* __restrict__ part) {
    __shared__ int s[SCAN_B];
    const int tid = threadIdx.x;
    const int i = blockIdx.x * SCAN_B + tid;
    int v = (i < NN) ? deg[i] : 0;
    s[tid] = v;
    __syncthreads();
    for (int o = 1; o < SCAN_B; o <<= 1) {
        int t = (tid >= o) ? s[tid - o] : 0;
        __syncthreads();
        s[tid] += t;
        __syncthreads();
    }
    if (i < NN) rowptr[i] = s[tid] - v;          // exclusive within block
    if (tid == SCAN_B - 1) part[blockIdx.x] = s[SCAN_B - 1];
}

// scan the 196 block totals (single block)
__global__ __launch_bounds__(SCAN_B) void k_scan2(int* __restrict__ part) {
    __shared__ int s[SCAN_B];
    const int tid = threadIdx.x;
    int v = (tid < NBLK) ? part[tid] : 0;
    s[tid] = v;
    __syncthreads();
    for (int o = 1; o < SCAN_B; o <<= 1) {
        int t = (tid >= o) ? s[tid - o] : 0;
        __syncthreads();
        s[tid] += t;
        __syncthreads();
    }
    if (tid < NBLK) part[tid] = s[tid] - v;      // exclusive block offsets
}

// add block offsets; also init cursor for scatter
__global__ void k_scan3(int* __restrict__ rowptr, int* __restrict__ cursor,
                        const int* __restrict__ part) {
    int i = blockIdx.x * blockDim.x + threadIdx.x;
    if (i >= NN) return;
    int r = rowptr[i] + part[i >> 8];
    rowptr[i] = r;
    cursor[i] = r;
}

// scatter edges into CSR order (src only; softmax is shift-invariant so we
// never need per-edge state keyed by original edge id)
__global__ void k_scatter(const int* __restrict__ ei, int* __restrict__ cursor,
                          int* __restrict__ csr_src) {
    int e = blockIdx.x * blockDim.x + threadIdx.x;
    if (e >= NE) return;
    int s = ei[e], d = ei[NE + e];
    int pos = atomicAdd(&cursor[d], 1);
    csr_src[pos] = s;
}

// ---------------- layer 1 GEMM: xl1 = x@W1l, xr1 = x@W1r ----------------
// grid (ceil(NN/64), 2); W staged in LDS once per block (kills L2 re-reads)

#define G1N 64
__global__ __launch_bounds__(256) void k_gemm1(const float* __restrict__ x,
                                               const float* __restrict__ W1l,
                                               const float* __restrict__ W1r,
                                               float* __restrict__ xl,
                                               float* __restrict__ xr) {
    __shared__ float Ws[FIN * 64];       // 32 KB
    __shared__ float xs[G1N][FIN + 1];   // pad -> conflict-free row reads
    const float* __restrict__ W = blockIdx.y ? W1r : W1l;
    float* __restrict__ o = blockIdx.y ? xr : xl;
    const int n0 = blockIdx.x * G1N;
    const int t = threadIdx.x;

    for (int i = t; i < FIN * 64; i += 256) Ws[i] = W[i];
    for (int i = t; i < G1N * FIN; i += 256) {
        int r = i >> 7, c = i & 127;
        int n = n0 + r;
        xs[r][c] = (n < NN) ? x[(size_t)n * FIN + c] : 0.f;
    }
    __syncthreads();

    const int tc = t & 15;   // col group: cols tc*4 .. tc*4+3
    const int tr = t >> 4;   // node group: nodes tr*4 .. tr*4+3
    float acc[4][4] = {};
#pragma unroll 4
    for (int k = 0; k < FIN; ++k) {
        float4 wv = *(const float4*)&Ws[k * 64 + tc * 4];
        float xk0 = xs[tr * 4 + 0][k];
        float xk1 = xs[tr * 4 + 1][k];
        float xk2 = xs[tr * 4 + 2][k];
        float xk3 = xs[tr * 4 + 3][k];
        acc[0][0] = fmaf(xk0, wv.x, acc[0][0]); acc[0][1] = fmaf(xk0, wv.y, acc[0][1]);
        acc[0][2] = fmaf(xk0, wv.z, acc[0][2]); acc[0][3] = fmaf(xk0, wv.w, acc[0][3]);
        acc[1][0] = fmaf(xk1, wv.x, acc[1][0]); acc[1][1] = fmaf(xk1, wv.y, acc[1][1]);
        acc[1][2] = fmaf(xk1, wv.z, acc[1][2]); acc[1][3] = fmaf(xk1, wv.w, acc[1][3]);
        acc[2][0] = fmaf(xk2, wv.x, acc[2][0]); acc[2][1] = fmaf(xk2, wv.y, acc[2][1]);
        acc[2][2] = fmaf(xk2, wv.z, acc[2][2]); acc[2][3] = fmaf(xk2, wv.w, acc[2][3]);
        acc[3][0] = fmaf(xk3, wv.x, acc[3][0]); acc[3][1] = fmaf(xk3, wv.y, acc[3][1]);
        acc[3][2] = fmaf(xk3, wv.z, acc[3][2]); acc[3][3] = fmaf(xk3, wv.w, acc[3][3]);
    }
#pragma unroll
    for (int j = 0; j < 4; ++j) {
        int n = n0 + tr * 4 + j;
        if (n < NN) {
            float4 v = make_float4(acc[j][0], acc[j][1], acc[j][2], acc[j][3]);
            *(float4*)&o[(size_t)n * 64 + tc * 4] = v;
        }
    }
}

// ---------------- layer 1 fused aggregate ----------------
// one wave per dst node; lane = feature (h = lane>>4). Per edge: gather
// xl[src] row, logit via 16-lane butterfly, ex=exp(logit) (shift-free),
// accumulate denom and ex*xl. Epilogue: /denom, +b1, ELU.
__global__ __launch_bounds__(256) void k_agg1(const float* __restrict__ xl,
                                              const float* __restrict__ xr,
                                              const int* __restrict__ rowptr,
                                              const int* __restrict__ deg,
                                              const int* __restrict__ csr_src,
                                              const float* __restrict__ att1,
                                              const float* __restrict__ b1,
                                              float* __restrict__ hb) {
    const int node = blockIdx.x * 4 + (threadIdx.x >> 6);
    if (node >= NN) return;
    const int lane = threadIdx.x & 63;
    const float attf = att1[lane];                 // [4][16] flat == lane
    const float xrf = xr[(size_t)node * 64 + lane];
    const int start = rowptr[node];
    const int dg = deg[node];

    float denom = 0.f, acc = 0.f;
    for (int base = 0; base < dg; base += 64) {
        int idx = base + lane;
        int srcs = (idx < dg) ? csr_src[start + idx] : 0;
        int lim = dg - base; if (lim > 64) lim = 64;
        for (int jj = 0; jj < lim; ++jj) {
            int src = __shfl(srcs, jj);
            float xv = xl[(size_t)src * 64 + lane];
            float t = lrelu(xv + xrf) * attf;
            t += __shfl_xor(t, 1);
            t += __shfl_xor(t, 2);
            t += __shfl_xor(t, 4);
            t += __shfl_xor(t, 8);
            float ex = __expf(t);
            denom += ex;
            acc = fmaf(ex, xv, acc);
        }
    }
    float o = (dg > 0) ? acc / denom : 0.f;
    o += b1[lane];
    hb[(size_t)node * 64 + lane] = o > 0.f ? o : expm1f(o);
}

// ---------------- layer 2 GEMM ----------------
__global__ __launch_bounds__(64) void k_gemm2(const float* __restrict__ h,
                                              const float* __restrict__ Wl,
                                              const float* __restrict__ Wr,
                                              float* __restrict__ xl2,
                                              float* __restrict__ xr2) {
    __shared__ float hs[FMID];
    const int n = blockIdx.x;
    const int t = threadIdx.x;
    hs[t] = h[(size_t)n * FMID + t];
    __syncthreads();
    const int lane = t & 31;
    if (lane < NC) {
        const float* __restrict__ W = (t < 32) ? Wl : Wr;
        float acc = 0.f;
#pragma unroll 8
        for (int k = 0; k < FMID; ++k) acc = fmaf(hs[k], W[k * NC + lane], acc);
        float* __restrict__ o = (t < 32) ? xl2 : xr2;
        o[(size_t)n * NC + lane] = acc;
    }
}

// ---------------- layer 2 fused aggregate ----------------
// one wave per node; 4 groups of 16 lanes, group g handles edge j+g;
// features padded 10->16 (lanes c>=10 contribute 0).
__global__ __launch_bounds__(256) void k_agg2(const float* __restrict__ xl2,
                                              const float* __restrict__ xr2,
                                              const int* __restrict__ rowptr,
                                              const int* __restrict__ deg,
                                              const int* __restrict__ csr_src,
                                              const float* __restrict__ att2,
                                              const float* __restrict__ b2,
                                              float* __restrict__ out) {
    const int node = blockIdx.x * 4 + (threadIdx.x >> 6);
    if (node >= NN) return;
    const int lane = threadIdx.x & 63;
    const int g = lane >> 4, c = lane & 15;
    const bool fa = c < NC;
    const float attf = fa ? att2[c] : 0.f;
    const float xrf = fa ? xr2[(size_t)node * NC + c] : 0.f;
    const int start = rowptr[node];
    const int dg = deg[node];

    float denom = 0.f, acc = 0.f;
    for (int base = 0; base < dg; base += 64) {
        int idx = base + lane;
        int srcs = (idx < dg) ? csr_src[start + idx] : 0;
        int lim = dg - base; if (lim > 64) lim = 64;
        for (int jj = 0; jj < lim; jj += 4) {
            int j = jj + g;
            bool v = j < lim;
            int src = __shfl(srcs, j & 63);
            float xv = (v && fa) ? xl2[(size_t)src * NC + c] : 0.f;
            float t = lrelu(xv + xrf) * attf;
            t += __shfl_xor(t, 1);
            t += __shfl_xor(t, 2);
            t += __shfl_xor(t, 4);
            t += __shfl_xor(t, 8);
            float ex = v ? __expf(t) : 0.f;
            denom += ex;
            acc = fmaf(ex, xv, acc);
        }
    }
    // combine the 4 edge-groups (xor over g bits only)
    denom += __shfl_xor(denom, 16);
    denom += __shfl_xor(denom, 32);
    acc += __shfl_xor(acc, 16);
    acc += __shfl_xor(acc, 32);
    if (lane < NC) {
        float o = (dg > 0) ? acc / denom : 0.f;
        out[(size_t)node * NC + lane] = o + b2[lane];
    }
}

// ---------------- launch ----------------

extern "C" void kernel_launch(void* const* d_in, const int* in_sizes, int n_in,
                              void* d_out, int out_size, void* d_ws, size_t ws_size,
                              hipStream_t stream) {
    const float* x    = (const float*)d_in[0];
    const int*   ei   = (const int*)d_in[1];
    const float* W1l  = (const float*)d_in[2];
    const float* W1r  = (const float*)d_in[3];
    const float* att1 = (const float*)d_in[4];
    const float* b1   = (const float*)d_in[5];
    const float* W2l  = (const float*)d_in[6];
    const float* W2r  = (const float*)d_in[7];
    const float* att2 = (const float*)d_in[8];
    const float* b2   = (const float*)d_in[9];
    float* out = (float*)d_out;

    // workspace layout
    float* ws  = (float*)d_ws;
    float* xl1 = ws;                           // NN*64
    float* xr1 = xl1 + (size_t)NN * 64;        // NN*64
    float* hb  = xr1 + (size_t)NN * 64;        // NN*64
    float* xl2 = hb  + (size_t)NN * 64;        // NN*NC
    float* xr2 = xl2 + (size_t)NN * NC;        // NN*NC
    int*   ip  = (int*)(xr2 + (size_t)NN * NC);
    int* deg     = ip;                         // NN
    int* rowptr  = deg + NN;                   // NN
    int* cursor  = rowptr + NN;                // NN
    int* part    = cursor + NN;                // NBLK
    int* csr_src = part + NBLK;                // NE

    const int B = 256;

    // CSR build
    k_zero<<<(NN + B - 1) / B, B, 0, stream>>>(deg);
    k_count<<<(NE + B - 1) / B, B, 0, stream>>>(ei, deg);
    k_scan1<<<NBLK, SCAN_B, 0, stream>>>(deg, rowptr, part);
    k_scan2<<<1, SCAN_B, 0, stream>>>(part);
    k_scan3<<<(NN + B - 1) / B, B, 0, stream>>>(rowptr, cursor, part);
    k_scatter<<<(NE + B - 1) / B, B, 0, stream>>>(ei, cursor, csr_src);

    // layer 1
    k_gemm1<<<dim3((NN + G1N - 1) / G1N, 2), 256, 0, stream>>>(x, W1l, W1r, xl1, xr1);
    k_agg1<<<(NN + 3) / 4, 256, 0, stream>>>(xl1, xr1, rowptr, deg, csr_src, att1, b1, hb);

    // layer 2
    k_gemm2<<<NN, 64, 0, stream>>>(hb, W2l, W2r, xl2, xr2);
    k_agg2<<<(NN + 3) / 4, 256, 0, stream>>>(xl2, xr2, rowptr, deg, csr_src, att2, b2, out);
}

// Round 3
// 214.133 us; speedup vs baseline: 2.7454x; 1.3409x over previous
//
#include <hip/hip_runtime.h>
#include <math.h>

#define NN 50000
#define NE 800000
#define FIN 128
#define C1 16
#define H1 4
#define FMID 64   // H1*C1
#define NC 10     // classes, conv2 channels
#define NEG 0.2f

#define SCAN_B 256
#define NBLK ((NN + SCAN_B - 1) / SCAN_B)   // 196

__device__ __forceinline__ float lrelu(float v) {
    return v > 0.f ? v : NEG * v;
}

// sum over each 16-lane group using DPP (pure VALU — no LDS pipe)
template<int CTRL>
__device__ __forceinline__ float dpp_add(float x) {
    int y = __builtin_amdgcn_update_dpp(0, __float_as_int(x), CTRL, 0xF, 0xF, true);
    return x + __int_as_float(y);
}
__device__ __forceinline__ float red16(float t) {
    t = dpp_add<0xB1>(t);    // quad_perm [1,0,3,2]  : + lane^1
    t = dpp_add<0x4E>(t);    // quad_perm [2,3,0,1]  : + lane^2   -> quad sums
    t = dpp_add<0x141>(t);   // row_half_mirror (== ^4 once quad-uniform)
    t = dpp_add<0x140>(t);   // row_mirror      (== ^8 once half-uniform)
    return t;                // all 16 lanes of each group hold the group sum
}

// ---------------- CSR build ----------------

__global__ void k_zero(int* __restrict__ deg) {
    int i = blockIdx.x * blockDim.x + threadIdx.x;
    if (i < NN) deg[i] = 0;
}

__global__ void k_count(const int* __restrict__ ei, int* __restrict__ deg) {
    int e = blockIdx.x * blockDim.x + threadIdx.x;
    if (e >= NE) return;
    atomicAdd(&deg[ei[NE + e]], 1);
}

__global__ __launch_bounds__(SCAN_B) void k_scan1(const int* __restrict__ deg,
                                                  int* __restrict__ rowptr,
                                                  int* __restrict__ part) {
    __shared__ int s[SCAN_B];
    const int tid = threadIdx.x;
    const int i = blockIdx.x * SCAN_B + tid;
    int v = (i < NN) ? deg[i] : 0;
    s[tid] = v;
    __syncthreads();
    for (int o = 1; o < SCAN_B; o <<= 1) {
        int t = (tid >= o) ? s[tid - o] : 0;
        __syncthreads();
        s[tid] += t;
        __syncthreads();
    }
    if (i < NN) rowptr[i] = s[tid] - v;
    if (tid == SCAN_B - 1) part[blockIdx.x] = s[SCAN_B - 1];
}

__global__ __launch_bounds__(SCAN_B) void k_scan2(int* __restrict__ part) {
    __shared__ int s[SCAN_B];
    const int tid = threadIdx.x;
    int v = (tid < NBLK) ? part[tid] : 0;
    s[tid] = v;
    __syncthreads();
    for (int o = 1; o < SCAN_B; o <<= 1) {
        int t = (tid >= o) ? s[tid - o] : 0;
        __syncthreads();
        s[tid] += t;
        __syncthreads();
    }
    if (tid < NBLK) part[tid] = s[tid] - v;
}

__global__ void k_scan3(int* __restrict__ rowptr, int* __restrict__ cursor,
                        const int* __restrict__ part) {
    int i = blockIdx.x * blockDim.x + threadIdx.x;
    if (i >= NN) return;
    int r = rowptr[i] + part[i >> 8];
    rowptr[i] = r;
    cursor[i] = r;
}

__global__ void k_scatter(const int* __restrict__ ei, int* __restrict__ cursor,
                          int* __restrict__ csr_src) {
    int e = blockIdx.x * blockDim.x + threadIdx.x;
    if (e >= NE) return;
    int s = ei[e], d = ei[NE + e];
    int pos = atomicAdd(&cursor[d], 1);
    csr_src[pos] = s;
}

// ---------------- layer 1 GEMM ----------------
// tile: 128 nodes x 64 cols, 256 threads, thread = 8 nodes x 4 cols.
// W staged once (32KB); x staged transposed in 32-k chunks (16KB). 48KB LDS.
#define G1N 128
__global__ __launch_bounds__(256) void k_gemm1(const float* __restrict__ x,
                                               const float* __restrict__ W1l,
                                               const float* __restrict__ W1r,
                                               float* __restrict__ xl,
                                               float* __restrict__ xr) {
    __shared__ float Ws[FIN][64];        // [k][col] 32KB
    __shared__ float xsT[32][G1N];       // [k-in-chunk][node] 16KB
    const float* __restrict__ W = blockIdx.y ? W1r : W1l;
    float* __restrict__ o = blockIdx.y ? xr : xl;
    const int n0 = blockIdx.x * G1N;
    const int t = threadIdx.x;

    {   // stage W (coalesced float4)
        const float4* Wv = (const float4*)W;
        float4* Wsv = (float4*)&Ws[0][0];
        for (int i = t; i < FIN * 64 / 4; i += 256) Wsv[i] = Wv[i];
    }

    const int tn = t >> 4;   // node group: nodes tn*8 .. +7
    const int tc = t & 15;   // col group : cols tc*4 .. +3
    float acc[8][4] = {};

    const int sn = t >> 1;               // staging: node within tile
    const int koff = (t & 1) * 16;       // staging: k offset within chunk

    for (int kc = 0; kc < FIN; kc += 32) {
        __syncthreads();                 // readers of previous chunk done / W staged
        {
            int gn = n0 + sn;
            float4 v0, v1, v2, v3;
            if (gn < NN) {
                const float4* xrow = (const float4*)(x + (size_t)gn * FIN + kc + koff);
                v0 = xrow[0]; v1 = xrow[1]; v2 = xrow[2]; v3 = xrow[3];
            } else {
                v0 = v1 = v2 = v3 = make_float4(0.f, 0.f, 0.f, 0.f);
            }
            xsT[koff +  0][sn] = v0.x; xsT[koff +  1][sn] = v0.y;
            xsT[koff +  2][sn] = v0.z; xsT[koff +  3][sn] = v0.w;
            xsT[koff +  4][sn] = v1.x; xsT[koff +  5][sn] = v1.y;
            xsT[koff +  6][sn] = v1.z; xsT[koff +  7][sn] = v1.w;
            xsT[koff +  8][sn] = v2.x; xsT[koff +  9][sn] = v2.y;
            xsT[koff + 10][sn] = v2.z; xsT[koff + 11][sn] = v2.w;
            xsT[koff + 12][sn] = v3.x; xsT[koff + 13][sn] = v3.y;
            xsT[koff + 14][sn] = v3.z; xsT[koff + 15][sn] = v3.w;
        }
        __syncthreads();
#pragma unroll
        for (int k = 0; k < 32; ++k) {
            float4 wv = *(const float4*)&Ws[kc + k][tc * 4];
            float4 xa = *(const float4*)&xsT[k][tn * 8];
            float4 xb = *(const float4*)&xsT[k][tn * 8 + 4];
            float xn[8] = {xa.x, xa.y, xa.z, xa.w, xb.x, xb.y, xb.z, xb.w};
#pragma unroll
            for (int i = 0; i < 8; ++i) {
                acc[i][0] = fmaf(xn[i], wv.x, acc[i][0]);
                acc[i][1] = fmaf(xn[i], wv.y, acc[i][1]);
                acc[i][2] = fmaf(xn[i], wv.z, acc[i][2]);
                acc[i][3] = fmaf(xn[i], wv.w, acc[i][3]);
            }
        }
    }
#pragma unroll
    for (int i = 0; i < 8; ++i) {
        int n = n0 + tn * 8 + i;
        if (n < NN) {
            *(float4*)&o[(size_t)n * 64 + tc * 4] =
                make_float4(acc[i][0], acc[i][1], acc[i][2], acc[i][3]);
        }
    }
}

// ---------------- layer 1 fused aggregate ----------------
__global__ __launch_bounds__(256) void k_agg1(const float* __restrict__ xl,
                                              const float* __restrict__ xr,
                                              const int* __restrict__ rowptr,
                                              const int* __restrict__ deg,
                                              const int* __restrict__ csr_src,
                                              const float* __restrict__ att1,
                                              const float* __restrict__ b1,
                                              float* __restrict__ hb) {
    const int node = blockIdx.x * 4 + (threadIdx.x >> 6);
    if (node >= NN) return;
    const int lane = threadIdx.x & 63;
    const float attf = att1[lane];
    const float xrf = xr[(size_t)node * 64 + lane];
    const int start = rowptr[node];
    const int dg = deg[node];

    float denom = 0.f, acc = 0.f;
    for (int base = 0; base < dg; base += 64) {
        int idx = base + lane;
        int srcs = (idx < dg) ? csr_src[start + idx] : 0;
        int lim = dg - base; if (lim > 64) lim = 64;
        int jj = 0;
        for (; jj + 2 <= lim; jj += 2) {
            int s0 = __builtin_amdgcn_readlane(srcs, jj);
            int s1 = __builtin_amdgcn_readlane(srcs, jj + 1);
            float xv0 = xl[(size_t)s0 * 64 + lane];
            float xv1 = xl[(size_t)s1 * 64 + lane];
            float t0 = red16(lrelu(xv0 + xrf) * attf);
            float t1 = red16(lrelu(xv1 + xrf) * attf);
            float e0 = __expf(t0), e1 = __expf(t1);
            denom += e0 + e1;
            acc = fmaf(e0, xv0, acc);
            acc = fmaf(e1, xv1, acc);
        }
        if (jj < lim) {
            int s0 = __builtin_amdgcn_readlane(srcs, jj);
            float xv0 = xl[(size_t)s0 * 64 + lane];
            float t0 = red16(lrelu(xv0 + xrf) * attf);
            float e0 = __expf(t0);
            denom += e0;
            acc = fmaf(e0, xv0, acc);
        }
    }
    float o = (dg > 0) ? acc / denom : 0.f;
    o += b1[lane];
    hb[(size_t)node * 64 + lane] = o > 0.f ? o : expm1f(o);
}

// ---------------- layer 2 GEMM (node per thread, scalar W loads) ----------------
__global__ __launch_bounds__(256) void k_gemm2(const float* __restrict__ h,
                                               const float* __restrict__ W2l,
                                               const float* __restrict__ W2r,
                                               float* __restrict__ xl2,
                                               float* __restrict__ xr2) {
    int n = blockIdx.x * 256 + threadIdx.x;
    if (n >= NN) return;
    float al[NC] = {}, ar[NC] = {};
    const float4* hr = (const float4*)(h + (size_t)n * 64);
#pragma unroll 4
    for (int q = 0; q < 16; ++q) {
        float4 hv = hr[q];
        const float* __restrict__ wl = W2l + q * 4 * NC;
        const float* __restrict__ wr = W2r + q * 4 * NC;
#pragma unroll
        for (int c = 0; c < NC; ++c) {
            al[c] = fmaf(hv.x, wl[c],          al[c]);
            al[c] = fmaf(hv.y, wl[NC + c],     al[c]);
            al[c] = fmaf(hv.z, wl[2 * NC + c], al[c]);
            al[c] = fmaf(hv.w, wl[3 * NC + c], al[c]);
            ar[c] = fmaf(hv.x, wr[c],          ar[c]);
            ar[c] = fmaf(hv.y, wr[NC + c],     ar[c]);
            ar[c] = fmaf(hv.z, wr[2 * NC + c], ar[c]);
            ar[c] = fmaf(hv.w, wr[3 * NC + c], ar[c]);
        }
    }
#pragma unroll
    for (int c = 0; c < NC; ++c) xl2[(size_t)n * NC + c] = al[c];
#pragma unroll
    for (int c = 0; c < NC; ++c) xr2[(size_t)n * NC + c] = ar[c];
}

// ---------------- layer 2 fused aggregate ----------------
__global__ __launch_bounds__(256) void k_agg2(const float* __restrict__ xl2,
                                              const float* __restrict__ xr2,
                                              const int* __restrict__ rowptr,
                                              const int* __restrict__ deg,
                                              const int* __restrict__ csr_src,
                                              const float* __restrict__ att2,
                                              const float* __restrict__ b2,
                                              float* __restrict__ out) {
    const int node = blockIdx.x * 4 + (threadIdx.x >> 6);
    if (node >= NN) return;
    const int lane = threadIdx.x & 63;
    const int g = lane >> 4, c = lane & 15;
    const bool fa = c < NC;
    const float attf = fa ? att2[c] : 0.f;
    const float xrf = fa ? xr2[(size_t)node * NC + c] : 0.f;
    const int start = rowptr[node];
    const int dg = deg[node];

    float denom = 0.f, acc = 0.f;
    for (int base = 0; base < dg; base += 64) {
        int idx = base + lane;
        int srcs = (idx < dg) ? csr_src[start + idx] : 0;
        int lim = dg - base; if (lim > 64) lim = 64;
        for (int jj = 0; jj < lim; jj += 4) {
            int j = jj + g;
            bool v = j < lim;
            int src = __shfl(srcs, j & 63);
            float xv = (v && fa) ? xl2[(size_t)src * NC + c] : 0.f;
            float t = red16(lrelu(xv + xrf) * attf);
            float ex = v ? __expf(t) : 0.f;
            denom += ex;
            acc = fmaf(ex, xv, acc);
        }
    }
    denom += __shfl_xor(denom, 16);
    denom += __shfl_xor(denom, 32);
    acc += __shfl_xor(acc, 16);
    acc += __shfl_xor(acc, 32);
    if (lane < NC) {
        float o = (dg > 0) ? acc / denom : 0.f;
        out[(size_t)node * NC + lane] = o + b2[lane];
    }
}

// ---------------- launch ----------------

extern "C" void kernel_launch(void* const* d_in, const int* in_sizes, int n_in,
                              void* d_out, int out_size, void* d_ws, size_t ws_size,
                              hipStream_t stream) {
    const float* x    = (const float*)d_in[0];
    const int*   ei   = (const int*)d_in[1];
    const float* W1l  = (const float*)d_in[2];
    const float* W1r  = (const float*)d_in[3];
    const float* att1 = (const float*)d_in[4];
    const float* b1   = (const float*)d_in[5];
    const float* W2l  = (const float*)d_in[6];
    const float* W2r  = (const float*)d_in[7];
    const float* att2 = (const float*)d_in[8];
    const float* b2   = (const float*)d_in[9];
    float* out = (float*)d_out;

    float* ws  = (float*)d_ws;
    float* xl1 = ws;                           // NN*64
    float* xr1 = xl1 + (size_t)NN * 64;        // NN*64
    float* hb  = xr1 + (size_t)NN * 64;        // NN*64
    float* xl2 = hb  + (size_t)NN * 64;        // NN*NC
    float* xr2 = xl2 + (size_t)NN * NC;        // NN*NC
    int*   ip  = (int*)(xr2 + (size_t)NN * NC);
    int* deg     = ip;                         // NN
    int* rowptr  = deg + NN;                   // NN
    int* cursor  = rowptr + NN;                // NN
    int* part    = cursor + NN;                // NBLK
    int* csr_src = part + NBLK;                // NE

    const int B = 256;

    // CSR build
    k_zero<<<(NN + B - 1) / B, B, 0, stream>>>(deg);
    k_count<<<(NE + B - 1) / B, B, 0, stream>>>(ei, deg);
    k_scan1<<<NBLK, SCAN_B, 0, stream>>>(deg, rowptr, part);
    k_scan2<<<1, SCAN_B, 0, stream>>>(part);
    k_scan3<<<(NN + B - 1) / B, B, 0, stream>>>(rowptr, cursor, part);
    k_scatter<<<(NE + B - 1) / B, B, 0, stream>>>(ei, cursor, csr_src);

    // layer 1
    k_gemm1<<<dim3((NN + G1N - 1) / G1N, 2), 256, 0, stream>>>(x, W1l, W1r, xl1, xr1);
    k_agg1<<<(NN + 3) / 4, 256, 0, stream>>>(xl1, xr1, rowptr, deg, csr_src, att1, b1, hb);

    // layer 2
    k_gemm2<<<(NN + 255) / 256, 256, 0, stream>>>(hb, W2l, W2r, xl2, xr2);
    k_agg2<<<(NN + 3) / 4, 256, 0, stream>>>(xl2, xr2, rowptr, deg, csr_src, att2, b2, out);
}

// Round 4
// 135.247 us; speedup vs baseline: 4.3468x; 1.5833x over previous
//
#include <hip/hip_runtime.h>
#include <hip/hip_fp16.h>
#include <math.h>

#define NN 50000
#define NE 800000
#define FIN 128
#define NC 10
#define NEG 0.2f

#define NB 196        // coarse buckets = ceil(NN/256), bucket = dst>>8
#define CHUNK 4096    // edges per pass1 block
#define P1B ((NE + CHUNK - 1) / CHUNK)   // 196
#define CAP 5120      // temp capacity per bucket (mean 4082, sd 64 -> +16 sigma)
#define G1T ((NN + 127) / 128)           // 391 gemm1 tiles

typedef unsigned int uint;

__device__ __forceinline__ float lrelu(float v) {
    return v > 0.f ? v : NEG * v;
}

// sum over each 16-lane group using DPP (pure VALU - no LDS pipe)
template<int CTRL>
__device__ __forceinline__ float dpp_add(float x) {
    int y = __builtin_amdgcn_update_dpp(0, __float_as_int(x), CTRL, 0xF, 0xF, true);
    return x + __int_as_float(y);
}
__device__ __forceinline__ float red16(float t) {
    t = dpp_add<0xB1>(t);    // + lane^1
    t = dpp_add<0x4E>(t);    // + lane^2
    t = dpp_add<0x141>(t);   // row_half_mirror == ^4 once quad-uniform
    t = dpp_add<0x140>(t);   // row_mirror      == ^8 once half-uniform
    return t;
}

// exclusive scan of v across the 256 threads of the block; sc = scratch[256]
__device__ __forceinline__ int excl_scan256(int v, int* sc) {
    const int t = threadIdx.x;
    sc[t] = v;
    __syncthreads();
    for (int o = 1; o < 256; o <<= 1) {
        int u = (t >= o) ? sc[t - o] : 0;
        __syncthreads();
        sc[t] += u;
        __syncthreads();
    }
    return sc[t] - v;
}

// ---------------- fused kernel A: pass1 bucket-scatter || gemm1 ----------------

__device__ void pass1_body(const int* __restrict__ ei, uint* __restrict__ temp,
                           int* __restrict__ gcursor, char* smraw) {
    uint2* pairs = (uint2*)smraw;               // 32768 B
    int* h   = (int*)(smraw + 32768);           // 1024
    int* h2  = (int*)(smraw + 33792);           // 1024
    int* gb  = (int*)(smraw + 34816);           // 1024
    int* lb  = (int*)(smraw + 35840);           // 1024
    int* sc  = (int*)(smraw + 36864);           // 1024
    const int t = threadIdx.x;
    const int e0 = blockIdx.x * CHUNK;
    const int cnt = min(CHUNK, NE - e0);

    h[t] = 0; h2[t] = 0;
    __syncthreads();
    for (int i = t; i < cnt; i += 256) {
        int d = ei[NE + e0 + i];
        atomicAdd(&h[d >> 8], 1);
    }
    __syncthreads();
    const int hv = h[t];
    const int ex = excl_scan256(hv, sc);
    lb[t] = ex;
    if (t < NB && hv > 0) gb[t] = atomicAdd(&gcursor[t], hv);
    __syncthreads();
    for (int i = t; i < cnt; i += 256) {
        int s = ei[e0 + i];
        int d = ei[NE + e0 + i];
        int b = d >> 8;
        int r = atomicAdd(&h2[b], 1);
        pairs[lb[b] + r] = make_uint2((uint)s, (uint)d);
    }
    __syncthreads();
    // contiguous runs per bucket -> coalesced-ish global writes
    for (int i = t; i < cnt; i += 256) {
        uint2 p = pairs[i];
        int b = (int)(p.y >> 8);
        int pos = gb[b] + (i - lb[b]);
        if (pos < CAP) temp[b * CAP + pos] = (p.x << 8) | (p.y & 255u);
    }
}

__device__ void gemm1_body(const float* __restrict__ x, const float* __restrict__ W,
                           __half* __restrict__ xlh, float* __restrict__ xr,
                           bool toHalf, int n0, char* smraw) {
    float (*Ws)[64]  = (float(*)[64])smraw;            // 32 KB [k][col]
    float (*xsT)[128] = (float(*)[128])(smraw + 32768); // 16 KB [k][node]
    const int t = threadIdx.x;

    {   // stage W once (coalesced float4)
        const float4* Wv = (const float4*)W;
        float4* Wsv = (float4*)&Ws[0][0];
        for (int i = t; i < FIN * 64 / 4; i += 256) Wsv[i] = Wv[i];
    }

    const int tn = t >> 4;          // node group: nodes tn*8..+7
    const int tc = t & 15;          // col group : cols tc*4..+3
    float acc[8][4] = {};
    const int sn = t >> 1;          // staging node within tile
    const int koff = (t & 1) * 16;  // staging k offset

    for (int kc = 0; kc < FIN; kc += 32) {
        __syncthreads();
        {
            int gn = n0 + sn;
            float4 v0, v1, v2, v3;
            if (gn < NN) {
                const float4* xrow = (const float4*)(x + (size_t)gn * FIN + kc + koff);
                v0 = xrow[0]; v1 = xrow[1]; v2 = xrow[2]; v3 = xrow[3];
            } else {
                v0 = v1 = v2 = v3 = make_float4(0.f, 0.f, 0.f, 0.f);
            }
            xsT[koff +  0][sn] = v0.x; xsT[koff +  1][sn] = v0.y;
            xsT[koff +  2][sn] = v0.z; xsT[koff +  3][sn] = v0.w;
            xsT[koff +  4][sn] = v1.x; xsT[koff +  5][sn] = v1.y;
            xsT[koff +  6][sn] = v1.z; xsT[koff +  7][sn] = v1.w;
            xsT[koff +  8][sn] = v2.x; xsT[koff +  9][sn] = v2.y;
            xsT[koff + 10][sn] = v2.z; xsT[koff + 11][sn] = v2.w;
            xsT[koff + 12][sn] = v3.x; xsT[koff + 13][sn] = v3.y;
            xsT[koff + 14][sn] = v3.z; xsT[koff + 15][sn] = v3.w;
        }
        __syncthreads();
#pragma unroll
        for (int k = 0; k < 32; ++k) {
            float4 wv = *(const float4*)&Ws[kc + k][tc * 4];
            float4 xa = *(const float4*)&xsT[k][tn * 8];
            float4 xb = *(const float4*)&xsT[k][tn * 8 + 4];
            float xn[8] = {xa.x, xa.y, xa.z, xa.w, xb.x, xb.y, xb.z, xb.w};
#pragma unroll
            for (int i = 0; i < 8; ++i) {
                acc[i][0] = fmaf(xn[i], wv.x, acc[i][0]);
                acc[i][1] = fmaf(xn[i], wv.y, acc[i][1]);
                acc[i][2] = fmaf(xn[i], wv.z, acc[i][2]);
                acc[i][3] = fmaf(xn[i], wv.w, acc[i][3]);
            }
        }
    }
#pragma unroll
    for (int i = 0; i < 8; ++i) {
        int n = n0 + tn * 8 + i;
        if (n < NN) {
            if (toHalf) {
                union { __half h[4]; uint2 u; } uu;
                uu.h[0] = __float2half_rn(acc[i][0]);
                uu.h[1] = __float2half_rn(acc[i][1]);
                uu.h[2] = __float2half_rn(acc[i][2]);
                uu.h[3] = __float2half_rn(acc[i][3]);
                *(uint2*)(xlh + (size_t)n * 64 + tc * 4) = uu.u;
            } else {
                *(float4*)&xr[(size_t)n * 64 + tc * 4] =
                    make_float4(acc[i][0], acc[i][1], acc[i][2], acc[i][3]);
            }
        }
    }
}

__global__ __launch_bounds__(256) void k_fusedA(const float* __restrict__ x,
                                                const int* __restrict__ ei,
                                                const float* __restrict__ W1l,
                                                const float* __restrict__ W1r,
                                                __half* __restrict__ xlh,
                                                float* __restrict__ xr1,
                                                uint* __restrict__ temp,
                                                int* __restrict__ gcursor) {
    __shared__ __align__(16) char smraw[49152];
    if (blockIdx.x < P1B) {
        pass1_body(ei, temp, gcursor, smraw);
    } else {
        int g = blockIdx.x - P1B;
        bool left = g < G1T;
        int n0 = (left ? g : g - G1T) * 128;
        gemm1_body(x, left ? W1l : W1r, xlh, xr1, left, n0, smraw);
    }
}

// ---------------- pass2: per-bucket exact CSR (no global atomics) ----------------

__global__ __launch_bounds__(256) void k_pass2(const uint* __restrict__ temp,
                                               const int* __restrict__ gcursor,
                                               int* __restrict__ rowptr,
                                               int* __restrict__ deg,
                                               int* __restrict__ csr_src) {
    __shared__ uint P[CAP];
    __shared__ int nh[256], nbx[256], ncur[256], sc[256];
    __shared__ int csrbase_s;
    const int t = threadIdx.x;
    const int b = blockIdx.x;

    int gc = (t < NB) ? gcursor[t] : 0;
    int base_ex = excl_scan256(gc, sc);
    if (t == b) csrbase_s = base_ex;
    nh[t] = 0; ncur[t] = 0;
    __syncthreads();
    const int csrbase = csrbase_s;
    const int cnt = min(gcursor[b], CAP);

    for (int i = t; i < cnt; i += 256) {
        uint v = temp[b * CAP + i];
        P[i] = v;
        atomicAdd(&nh[v & 255u], 1);
    }
    __syncthreads();
    const int c = nh[t];
    const int nb_ex = excl_scan256(c, sc);
    nbx[t] = nb_ex;
    const int gnode = b * 256 + t;
    if (gnode < NN) { rowptr[gnode] = csrbase + nb_ex; deg[gnode] = c; }
    __syncthreads();
    for (int i = t; i < cnt; i += 256) {
        uint v = P[i];
        int l = (int)(v & 255u);
        int r = atomicAdd(&ncur[l], 1);
        csr_src[csrbase + nbx[l] + r] = (int)(v >> 8);
    }
}

// ---------------- layer 1 fused aggregate (fp16 gathers) ----------------

__global__ __launch_bounds__(256) void k_agg1(const __half* __restrict__ xlh,
                                              const float* __restrict__ xr,
                                              const int* __restrict__ rowptr,
                                              const int* __restrict__ deg,
                                              const int* __restrict__ csr_src,
                                              const float* __restrict__ att1,
                                              const float* __restrict__ b1,
                                              __half* __restrict__ hbh) {
    const int node = blockIdx.x * 4 + (threadIdx.x >> 6);
    if (node >= NN) return;
    const int lane = threadIdx.x & 63;
    const float attf = att1[lane];
    const float xrf = xr[(size_t)node * 64 + lane];
    const int start = rowptr[node];
    const int dg = deg[node];

    float denom = 0.f, acc = 0.f;
    for (int base = 0; base < dg; base += 64) {
        int idx = base + lane;
        int srcs = (idx < dg) ? csr_src[start + idx] : 0;
        int lim = dg - base; if (lim > 64) lim = 64;
        int jj = 0;
        for (; jj + 2 <= lim; jj += 2) {
            int s0 = __builtin_amdgcn_readlane(srcs, jj);
            int s1 = __builtin_amdgcn_readlane(srcs, jj + 1);
            float xv0 = __half2float(xlh[(size_t)s0 * 64 + lane]);
            float xv1 = __half2float(xlh[(size_t)s1 * 64 + lane]);
            float t0 = red16(lrelu(xv0 + xrf) * attf);
            float t1 = red16(lrelu(xv1 + xrf) * attf);
            float e0 = __expf(t0), e1 = __expf(t1);
            denom += e0 + e1;
            acc = fmaf(e0, xv0, acc);
            acc = fmaf(e1, xv1, acc);
        }
        if (jj < lim) {
            int s0 = __builtin_amdgcn_readlane(srcs, jj);
            float xv0 = __half2float(xlh[(size_t)s0 * 64 + lane]);
            float t0 = red16(lrelu(xv0 + xrf) * attf);
            float e0 = __expf(t0);
            denom += e0;
            acc = fmaf(e0, xv0, acc);
        }
    }
    float o = (dg > 0) ? acc / denom : 0.f;
    o += b1[lane];
    o = o > 0.f ? o : expm1f(o);
    hbh[(size_t)node * 64 + lane] = __float2half_rn(o);
}

// ---------------- layer 2 GEMM (fp16 in, node per thread) ----------------

__global__ __launch_bounds__(256) void k_gemm2(const __half* __restrict__ hbh,
                                               const float* __restrict__ W2l,
                                               const float* __restrict__ W2r,
                                               float* __restrict__ xl2p,
                                               float* __restrict__ xr2) {
    int n = blockIdx.x * 256 + threadIdx.x;
    if (n >= NN) return;
    float al[NC] = {}, ar[NC] = {};
    const uint2* hr = (const uint2*)(hbh + (size_t)n * 64);
#pragma unroll 4
    for (int q = 0; q < 16; ++q) {
        union { uint2 u; __half h[4]; } L;
        L.u = hr[q];
        float h0 = __half2float(L.h[0]), h1 = __half2float(L.h[1]);
        float h2 = __half2float(L.h[2]), h3 = __half2float(L.h[3]);
        const float* __restrict__ wl = W2l + q * 4 * NC;
        const float* __restrict__ wr = W2r + q * 4 * NC;
#pragma unroll
        for (int c = 0; c < NC; ++c) {
            al[c] = fmaf(h0, wl[c],          al[c]);
            al[c] = fmaf(h1, wl[NC + c],     al[c]);
            al[c] = fmaf(h2, wl[2 * NC + c], al[c]);
            al[c] = fmaf(h3, wl[3 * NC + c], al[c]);
            ar[c] = fmaf(h0, wr[c],          ar[c]);
            ar[c] = fmaf(h1, wr[NC + c],     ar[c]);
            ar[c] = fmaf(h2, wr[2 * NC + c], ar[c]);
            ar[c] = fmaf(h3, wr[3 * NC + c], ar[c]);
        }
    }
#pragma unroll
    for (int c = 0; c < NC; ++c) xl2p[(size_t)n * 16 + c] = al[c];
#pragma unroll
    for (int c = 0; c < NC; ++c) xr2[(size_t)n * NC + c] = ar[c];
}

// ---------------- layer 2 fused aggregate (64B-aligned 1-line gathers) ----------------

__global__ __launch_bounds__(256) void k_agg2(const float* __restrict__ xl2p,
                                              const float* __restrict__ xr2,
                                              const int* __restrict__ rowptr,
                                              const int* __restrict__ deg,
                                              const int* __restrict__ csr_src,
                                              const float* __restrict__ att2,
                                              const float* __restrict__ b2,
                                              float* __restrict__ out) {
    const int node = blockIdx.x * 4 + (threadIdx.x >> 6);
    if (node >= NN) return;
    const int lane = threadIdx.x & 63;
    const int g = lane >> 4, c = lane & 15;
    const bool fa = c < NC;
    const float attf = fa ? att2[c] : 0.f;
    const float xrf = fa ? xr2[(size_t)node * NC + c] : 0.f;
    const int start = rowptr[node];
    const int dg = deg[node];

    float denom = 0.f, acc = 0.f;
    for (int base = 0; base < dg; base += 64) {
        int idx = base + lane;
        int srcs = (idx < dg) ? csr_src[start + idx] : 0;
        int lim = dg - base; if (lim > 64) lim = 64;
        for (int jj = 0; jj < lim; jj += 4) {
            int j = jj + g;
            bool v = j < lim;
            int src = __shfl(srcs, j & 63);
            float xv = (v && fa) ? xl2p[(size_t)src * 16 + c] : 0.f;
            float t = red16(lrelu(xv + xrf) * attf);
            float ex = v ? __expf(t) : 0.f;
            denom += ex;
            acc = fmaf(ex, xv, acc);
        }
    }
    denom += __shfl_xor(denom, 16);
    denom += __shfl_xor(denom, 32);
    acc += __shfl_xor(acc, 16);
    acc += __shfl_xor(acc, 32);
    if (lane < NC) {
        float o = (dg > 0) ? acc / denom : 0.f;
        out[(size_t)node * NC + lane] = o + b2[lane];
    }
}

// ---------------- launch ----------------

extern "C" void kernel_launch(void* const* d_in, const int* in_sizes, int n_in,
                              void* d_out, int out_size, void* d_ws, size_t ws_size,
                              hipStream_t stream) {
    const float* x    = (const float*)d_in[0];
    const int*   ei   = (const int*)d_in[1];
    const float* W1l  = (const float*)d_in[2];
    const float* W1r  = (const float*)d_in[3];
    const float* att1 = (const float*)d_in[4];
    const float* b1   = (const float*)d_in[5];
    const float* W2l  = (const float*)d_in[6];
    const float* W2r  = (const float*)d_in[7];
    const float* att2 = (const float*)d_in[8];
    const float* b2   = (const float*)d_in[9];
    float* out = (float*)d_out;

    char* w = (char*)d_ws;
    size_t off = 0;
    auto alloc = [&](size_t bytes) -> void* {
        void* p = w + off;
        off = (off + bytes + 255) & ~(size_t)255;
        return p;
    };
    __half* xlh   = (__half*)alloc((size_t)NN * 64 * 2);
    float*  xr1   = (float*)alloc((size_t)NN * 64 * 4);
    __half* hbh   = (__half*)alloc((size_t)NN * 64 * 2);
    float*  xl2p  = (float*)alloc((size_t)NN * 16 * 4);
    float*  xr2   = (float*)alloc((size_t)NN * NC * 4);
    uint*   temp  = (uint*)alloc((size_t)NB * CAP * 4);
    int*  gcursor = (int*)alloc((size_t)NB * 4);
    int*  rowptr  = (int*)alloc((size_t)NN * 4);
    int*  deg     = (int*)alloc((size_t)NN * 4);
    int*  csr_src = (int*)alloc((size_t)NE * 4);

    hipMemsetAsync(gcursor, 0, NB * 4, stream);

    k_fusedA<<<P1B + 2 * G1T, 256, 0, stream>>>(x, ei, W1l, W1r, xlh, xr1, temp, gcursor);
    k_pass2<<<NB, 256, 0, stream>>>(temp, gcursor, rowptr, deg, csr_src);
    k_agg1<<<(NN + 3) / 4, 256, 0, stream>>>(xlh, xr1, rowptr, deg, csr_src, att1, b1, hbh);
    k_gemm2<<<(NN + 255) / 256, 256, 0, stream>>>(hbh, W2l, W2r, xl2p, xr2);
    k_agg2<<<(NN + 3) / 4, 256, 0, stream>>>(xl2p, xr2, rowptr, deg, csr_src, att2, b2, out);
}

// Round 6
// 121.591 us; speedup vs baseline: 4.8350x; 1.1123x over previous
//
#include <hip/hip_runtime.h>
#include <math.h>

#define NN 50000
#define NE 800000
#define FIN 128
#define NC 10
#define NEG 0.2f

#define NB 196        // coarse buckets = ceil(NN/256), bucket = dst>>8
#define CHUNK 4096    // edges per pass1 block
#define P1B ((NE + CHUNK - 1) / CHUNK)   // 196
#define CAP 5120      // temp capacity per bucket
#define G1T ((NN + 127) / 128)           // 391 gemm1 tiles

typedef unsigned int uint;
typedef unsigned char uchar;
typedef _Float16 h2 __attribute__((ext_vector_type(2)));
typedef __fp16 hb2 __attribute__((ext_vector_type(2)));
union U2H { uint u; h2 h; };

// pack 2 floats -> half2 bits (builtin returns __fp16v2; go through a union)
__device__ __forceinline__ uint pkrtz_u(float a, float b) {
    union { hb2 f; uint u; } r;
    r.f = __builtin_amdgcn_cvt_pkrtz(a, b);
    return r.u;
}

__device__ __forceinline__ float dot2f(h2 a, h2 b, float c) {
#if __has_builtin(__builtin_amdgcn_fdot2)
    return __builtin_amdgcn_fdot2(a, b, c, false);
#else
    return fmaf((float)a.x, (float)b.x, fmaf((float)a.y, (float)b.y, c));
#endif
}

// packed leaky-relu: max(v, 0.2*v)
__device__ __forceinline__ h2 lrelu2(h2 v) {
    return __builtin_elementwise_max(v, v * (_Float16)0.2f);
}

template<int CTRL>
__device__ __forceinline__ float dpp_add(float x) {
    int y = __builtin_amdgcn_update_dpp(0, __float_as_int(x), CTRL, 0xF, 0xF, true);
    return x + __int_as_float(y);
}
// sum over aligned 8-lane groups (quad xor1, xor2, then half-row mirror)
__device__ __forceinline__ float red8(float t) {
    t = dpp_add<0xB1>(t);
    t = dpp_add<0x4E>(t);
    t = dpp_add<0x141>(t);
    return t;
}

__device__ __forceinline__ int excl_scan256(int v, int* sc) {
    const int t = threadIdx.x;
    sc[t] = v;
    __syncthreads();
    for (int o = 1; o < 256; o <<= 1) {
        int u = (t >= o) ? sc[t - o] : 0;
        __syncthreads();
        sc[t] += u;
        __syncthreads();
    }
    return sc[t] - v;
}

// ---------------- fused kernel A: pass1 bucket-scatter || gemm1(f16) ----------------

__device__ void pass1_body(const int* __restrict__ ei, uint* __restrict__ temp,
                           int* __restrict__ gcursor, char* smraw) {
    uint*  pk = (uint*)smraw;                 // 16384 B [4096]
    uchar* bk = (uchar*)(smraw + 16384);      // 4096 B
    int* h  = (int*)(smraw + 20480);          // 1024
    int* h2_ = (int*)(smraw + 21504);         // 1024
    int* gb = (int*)(smraw + 22528);          // 1024
    int* lb = (int*)(smraw + 23552);          // 1024
    int* sc = (int*)(smraw + 24576);          // 1024
    const int t = threadIdx.x;
    const int e0 = blockIdx.x * CHUNK;
    const int cnt = min(CHUNK, NE - e0);

    h[t] = 0; h2_[t] = 0;
    __syncthreads();
    for (int i = t; i < cnt; i += 256) {
        int d = ei[NE + e0 + i];
        atomicAdd(&h[d >> 8], 1);
    }
    __syncthreads();
    const int hv = h[t];
    const int ex = excl_scan256(hv, sc);
    lb[t] = ex;
    if (t < NB && hv > 0) gb[t] = atomicAdd(&gcursor[t], hv);
    __syncthreads();
    for (int i = t; i < cnt; i += 256) {
        int s = ei[e0 + i];
        int d = ei[NE + e0 + i];
        int b = d >> 8;
        int r = atomicAdd(&h2_[b], 1);
        int pos = lb[b] + r;
        pk[pos] = ((uint)s << 8) | ((uint)d & 255u);
        bk[pos] = (uchar)b;
    }
    __syncthreads();
    for (int i = t; i < cnt; i += 256) {
        uint v = pk[i];
        int b = bk[i];
        int pos = gb[b] + (i - lb[b]);
        if (pos < CAP) temp[b * CAP + pos] = v;
    }
}

// xl/xr stored as half2 pairs: oh2[n*32 + pair]
__device__ void gemm1_body(const float* __restrict__ x, const float* __restrict__ W,
                           uint* __restrict__ oh2, int n0, char* smraw) {
    uint (*Wsh)[64]  = (uint(*)[64])smraw;             // [64 kp][64 col] 16KB
    uint (*xTh)[128] = (uint(*)[128])(smraw + 16384);  // [16 kp][128 node] 8KB
    const int t = threadIdx.x;

    for (int i = t; i < 4096; i += 256) {   // stage W as k-paired half2
        int kp = i >> 6, col = i & 63;
        Wsh[kp][col] = pkrtz_u(W[(2 * kp) * 64 + col], W[(2 * kp + 1) * 64 + col]);
    }

    const int tn = t >> 4;          // node group: nodes tn*8..+7
    const int tc = t & 15;          // col group : cols tc*4..+3
    float acc[8][4] = {};
    const int sn = t >> 1;          // staging node 0..127
    const int kp0 = (t & 1) * 8;    // staging k-pair offset within chunk

    for (int kc = 0; kc < FIN; kc += 32) {
        __syncthreads();
        {
            int gn = n0 + sn;
            float4 v0, v1, v2, v3;
            if (gn < NN) {
                const float4* xr_ = (const float4*)(x + (size_t)gn * FIN + kc + kp0 * 2);
                v0 = xr_[0]; v1 = xr_[1]; v2 = xr_[2]; v3 = xr_[3];
            } else {
                v0 = v1 = v2 = v3 = make_float4(0.f, 0.f, 0.f, 0.f);
            }
            xTh[kp0 + 0][sn] = pkrtz_u(v0.x, v0.y);
            xTh[kp0 + 1][sn] = pkrtz_u(v0.z, v0.w);
            xTh[kp0 + 2][sn] = pkrtz_u(v1.x, v1.y);
            xTh[kp0 + 3][sn] = pkrtz_u(v1.z, v1.w);
            xTh[kp0 + 4][sn] = pkrtz_u(v2.x, v2.y);
            xTh[kp0 + 5][sn] = pkrtz_u(v2.z, v2.w);
            xTh[kp0 + 6][sn] = pkrtz_u(v3.x, v3.y);
            xTh[kp0 + 7][sn] = pkrtz_u(v3.z, v3.w);
        }
        __syncthreads();
        const int kpc = kc >> 1;
#pragma unroll
        for (int kp = 0; kp < 16; ++kp) {
            uint4 wv = *(const uint4*)&Wsh[kpc + kp][tc * 4];
            uint4 xa = *(const uint4*)&xTh[kp][tn * 8];
            uint4 xb = *(const uint4*)&xTh[kp][tn * 8 + 4];
            U2H w0, w1, w2, w3, x0, x1, x2, x3, x4, x5, x6, x7;
            w0.u = wv.x; w1.u = wv.y; w2.u = wv.z; w3.u = wv.w;
            x0.u = xa.x; x1.u = xa.y; x2.u = xa.z; x3.u = xa.w;
            x4.u = xb.x; x5.u = xb.y; x6.u = xb.z; x7.u = xb.w;
            h2 xs[8] = {x0.h, x1.h, x2.h, x3.h, x4.h, x5.h, x6.h, x7.h};
#pragma unroll
            for (int i = 0; i < 8; ++i) {
                acc[i][0] = dot2f(xs[i], w0.h, acc[i][0]);
                acc[i][1] = dot2f(xs[i], w1.h, acc[i][1]);
                acc[i][2] = dot2f(xs[i], w2.h, acc[i][2]);
                acc[i][3] = dot2f(xs[i], w3.h, acc[i][3]);
            }
        }
    }
#pragma unroll
    for (int i = 0; i < 8; ++i) {
        int n = n0 + tn * 8 + i;
        if (n < NN) {
            uint p0 = pkrtz_u(acc[i][0], acc[i][1]);
            uint p1 = pkrtz_u(acc[i][2], acc[i][3]);
            *(uint2*)&oh2[(size_t)n * 32 + tc * 2] = make_uint2(p0, p1);
        }
    }
}

__global__ __launch_bounds__(256) void k_fusedA(const float* __restrict__ x,
                                                const int* __restrict__ ei,
                                                const float* __restrict__ W1l,
                                                const float* __restrict__ W1r,
                                                uint* __restrict__ xlh2,
                                                uint* __restrict__ xrh2,
                                                uint* __restrict__ temp,
                                                int* __restrict__ gcursor) {
    __shared__ __align__(16) char smraw[25600];
    if (blockIdx.x < P1B) {
        pass1_body(ei, temp, gcursor, smraw);
    } else {
        int g = blockIdx.x - P1B;
        bool left = g < G1T;
        int n0 = (left ? g : g - G1T) * 128;
        gemm1_body(x, left ? W1l : W1r, left ? xlh2 : xrh2, n0, smraw);
    }
}

// ---------------- pass2: per-bucket exact CSR ----------------

__global__ __launch_bounds__(256) void k_pass2(const uint* __restrict__ temp,
                                               const int* __restrict__ gcursor,
                                               int* __restrict__ rowptr,
                                               int* __restrict__ deg,
                                               int* __restrict__ csr_src) {
    __shared__ uint P[CAP];
    __shared__ int nh[256], nbx[256], ncur[256], sc[256];
    __shared__ int csrbase_s;
    const int t = threadIdx.x;
    const int b = blockIdx.x;

    int gc = (t < NB) ? gcursor[t] : 0;
    int base_ex = excl_scan256(gc, sc);
    if (t == b) csrbase_s = base_ex;
    nh[t] = 0; ncur[t] = 0;
    __syncthreads();
    const int csrbase = csrbase_s;
    const int cnt = min(gcursor[b], CAP);

    for (int i = t; i < cnt; i += 256) {
        uint v = temp[b * CAP + i];
        P[i] = v;
        atomicAdd(&nh[v & 255u], 1);
    }
    __syncthreads();
    const int c = nh[t];
    const int nb_ex = excl_scan256(c, sc);
    nbx[t] = nb_ex;
    const int gnode = b * 256 + t;
    if (gnode < NN) { rowptr[gnode] = csrbase + nb_ex; deg[gnode] = c; }
    __syncthreads();
    for (int i = t; i < cnt; i += 256) {
        uint v = P[i];
        int l = (int)(v & 255u);
        int r = atomicAdd(&ncur[l], 1);
        csr_src[csrbase + nbx[l] + r] = (int)(v >> 8);
    }
}

// ---------------- layer 1 aggregate: half2 lanes, 2 edges per wave-iter ----------------

__global__ __launch_bounds__(256) void k_agg1(const uint* __restrict__ xlh2,
                                              const uint* __restrict__ xrh2,
                                              const int* __restrict__ rowptr,
                                              const int* __restrict__ deg,
                                              const int* __restrict__ csr_src,
                                              const float* __restrict__ att1,
                                              const float* __restrict__ b1,
                                              uint* __restrict__ hbh2) {
    const int node = blockIdx.x * 4 + (threadIdx.x >> 6);
    if (node >= NN) return;
    const int lane = threadIdx.x & 63;
    const int fl = lane & 31;        // feature-pair
    const int hid = lane >> 5;       // edge-half id
    float2 av = *(const float2*)&att1[2 * fl];
    U2H att; att.u = pkrtz_u(av.x, av.y);
    U2H xrf; xrf.u = xrh2[(size_t)node * 32 + fl];
    const int start = rowptr[node];
    const int dg = deg[node];
    const int permbase = (lane & 32) >> 3;   // 0 or 4

    float denom = 0.f, acc0 = 0.f, acc1 = 0.f;
    for (int base = 0; base < dg; base += 64) {
        int idx = base + lane;
        int srcs = (idx < dg) ? csr_src[start + idx] : 0;
        int rem = dg - base; if (rem > 64) rem = 64;
        int iters = (rem + 1) >> 1;
        int thr = (rem - hid + 1) >> 1;      // edge (2j+hid) valid iff j < thr
        for (int jj = 0; jj < iters; ++jj) {
            int src = __builtin_amdgcn_ds_bpermute(jj * 8 + permbase, srcs);
            U2H xv; xv.u = xlh2[(size_t)src * 32 + fl];
            h2 s = xv.h + xrf.h;
            float t = dot2f(lrelu2(s), att.h, 0.f);
            t = red8(t);
            float ex = (jj < thr) ? __expf(t) : 0.f;
            denom += ex;
            acc0 = fmaf(ex, (float)xv.h.x, acc0);
            acc1 = fmaf(ex, (float)xv.h.y, acc1);
        }
    }
    denom += __shfl_xor(denom, 32);
    acc0  += __shfl_xor(acc0, 32);
    acc1  += __shfl_xor(acc1, 32);
    if (lane < 32) {
        float r = (dg > 0) ? (1.0f / denom) : 0.f;
        float2 bv = *(const float2*)&b1[2 * fl];
        float o0 = fmaf(acc0, r, bv.x);
        float o1 = fmaf(acc1, r, bv.y);
        o0 = o0 > 0.f ? o0 : expm1f(o0);
        o1 = o1 > 0.f ? o1 : expm1f(o1);
        hbh2[(size_t)node * 32 + fl] = pkrtz_u(o0, o1);
    }
}

// ---------------- layer 2 GEMM: node per thread, packed half2 outputs ----------------

__global__ __launch_bounds__(256) void k_gemm2(const uint* __restrict__ hbh2,
                                               const float* __restrict__ W2l,
                                               const float* __restrict__ W2r,
                                               uint* __restrict__ xl2h,
                                               uint* __restrict__ xr2h) {
    int n = blockIdx.x * 256 + threadIdx.x;
    if (n >= NN) return;
    float al[NC] = {}, ar[NC] = {};
    const uint4* hr4 = (const uint4*)(hbh2 + (size_t)n * 32);
#pragma unroll
    for (int q = 0; q < 8; ++q) {
        uint4 qq = hr4[q];
        uint uu[4] = {qq.x, qq.y, qq.z, qq.w};
#pragma unroll
        for (int j = 0; j < 4; ++j) {
            U2H hh; hh.u = uu[j];
            float f0 = (float)hh.h.x, f1 = (float)hh.h.y;
            int k = q * 8 + j * 2;
            const float* wl0 = W2l + k * NC;
            const float* wr0 = W2r + k * NC;
#pragma unroll
            for (int c = 0; c < NC; ++c) {
                al[c] = fmaf(f0, wl0[c], fmaf(f1, wl0[NC + c], al[c]));
                ar[c] = fmaf(f0, wr0[c], fmaf(f1, wr0[NC + c], ar[c]));
            }
        }
    }
    uint p0 = pkrtz_u(al[0], al[1]);
    uint p1 = pkrtz_u(al[2], al[3]);
    uint p2 = pkrtz_u(al[4], al[5]);
    uint p3 = pkrtz_u(al[6], al[7]);
    uint p4 = pkrtz_u(al[8], al[9]);
    *(uint4*)&xl2h[(size_t)n * 8]     = make_uint4(p0, p1, p2, p3);
    *(uint4*)&xl2h[(size_t)n * 8 + 4] = make_uint4(p4, 0u, 0u, 0u);
    p0 = pkrtz_u(ar[0], ar[1]);
    p1 = pkrtz_u(ar[2], ar[3]);
    p2 = pkrtz_u(ar[4], ar[5]);
    p3 = pkrtz_u(ar[6], ar[7]);
    p4 = pkrtz_u(ar[8], ar[9]);
    *(uint4*)&xr2h[(size_t)n * 8]     = make_uint4(p0, p1, p2, p3);
    *(uint4*)&xr2h[(size_t)n * 8 + 4] = make_uint4(p4, 0u, 0u, 0u);
}

// ---------------- layer 2 aggregate: 8 edges per wave-iter ----------------

__global__ __launch_bounds__(256) void k_agg2(const uint* __restrict__ xl2h,
                                              const uint* __restrict__ xr2h,
                                              const int* __restrict__ rowptr,
                                              const int* __restrict__ deg,
                                              const int* __restrict__ csr_src,
                                              const float* __restrict__ att2,
                                              const float* __restrict__ b2,
                                              float* __restrict__ out) {
    const int node = blockIdx.x * 4 + (threadIdx.x >> 6);
    if (node >= NN) return;
    const int lane = threadIdx.x & 63;
    const int fp = lane & 7;         // feature-pair (0..4 real, 5..7 pad)
    const int eg = lane >> 3;        // edge group 0..7
    U2H att;
    if (fp < 5) {
        float2 av = *(const float2*)&att2[2 * fp];
        att.u = pkrtz_u(av.x, av.y);
    } else {
        att.u = 0;
    }
    U2H xrf; xrf.u = xr2h[(size_t)node * 8 + fp];
    const int start = rowptr[node];
    const int dg = deg[node];
    const int permbase = eg * 4;

    float denom = 0.f, acc0 = 0.f, acc1 = 0.f;
    for (int base = 0; base < dg; base += 64) {
        int idx = base + lane;
        int srcs = (idx < dg) ? csr_src[start + idx] : 0;
        int rem = dg - base; if (rem > 64) rem = 64;
        int iters = (rem + 7) >> 3;
        int thr = (rem - eg + 7) >> 3;       // edge (8j+eg) valid iff j < thr
        for (int jj = 0; jj < iters; ++jj) {
            int src = __builtin_amdgcn_ds_bpermute(jj * 32 + permbase, srcs);
            U2H xv; xv.u = xl2h[(size_t)src * 8 + fp];
            h2 s = xv.h + xrf.h;
            float t = dot2f(lrelu2(s), att.h, 0.f);
            t = red8(t);
            float ex = (jj < thr) ? __expf(t) : 0.f;
            denom += ex;
            acc0 = fmaf(ex, (float)xv.h.x, acc0);
            acc1 = fmaf(ex, (float)xv.h.y, acc1);
        }
    }
#pragma unroll
    for (int m = 8; m <= 32; m <<= 1) {
        denom += __shfl_xor(denom, m);
        acc0  += __shfl_xor(acc0, m);
        acc1  += __shfl_xor(acc1, m);
    }
    if (lane < 5) {   // eg==0, fp<5
        float r = (dg > 0) ? (1.0f / denom) : 0.f;
        float2 o;
        o.x = fmaf(acc0, r, b2[2 * fp]);
        o.y = fmaf(acc1, r, b2[2 * fp + 1]);
        *(float2*)&out[(size_t)node * NC + 2 * fp] = o;
    }
}

// ---------------- launch ----------------

extern "C" void kernel_launch(void* const* d_in, const int* in_sizes, int n_in,
                              void* d_out, int out_size, void* d_ws, size_t ws_size,
                              hipStream_t stream) {
    const float* x    = (const float*)d_in[0];
    const int*   ei   = (const int*)d_in[1];
    const float* W1l  = (const float*)d_in[2];
    const float* W1r  = (const float*)d_in[3];
    const float* att1 = (const float*)d_in[4];
    const float* b1   = (const float*)d_in[5];
    const float* W2l  = (const float*)d_in[6];
    const float* W2r  = (const float*)d_in[7];
    const float* att2 = (const float*)d_in[8];
    const float* b2   = (const float*)d_in[9];
    float* out = (float*)d_out;

    char* w = (char*)d_ws;
    size_t off = 0;
    auto alloc = [&](size_t bytes) -> void* {
        void* p = w + off;
        off = (off + bytes + 255) & ~(size_t)255;
        return p;
    };
    uint* xlh2   = (uint*)alloc((size_t)NN * 32 * 4);
    uint* xrh2   = (uint*)alloc((size_t)NN * 32 * 4);
    uint* hbh2   = (uint*)alloc((size_t)NN * 32 * 4);
    uint* xl2h   = (uint*)alloc((size_t)NN * 8 * 4);
    uint* xr2h   = (uint*)alloc((size_t)NN * 8 * 4);
    uint* temp   = (uint*)alloc((size_t)NB * CAP * 4);
    int*  gcursor = (int*)alloc((size_t)NB * 4);
    int*  rowptr  = (int*)alloc((size_t)NN * 4);
    int*  deg     = (int*)alloc((size_t)NN * 4);
    int*  csr_src = (int*)alloc((size_t)NE * 4);

    hipMemsetAsync(gcursor, 0, NB * 4, stream);

    k_fusedA<<<P1B + 2 * G1T, 256, 0, stream>>>(x, ei, W1l, W1r, xlh2, xrh2, temp, gcursor);
    k_pass2<<<NB, 256, 0, stream>>>(temp, gcursor, rowptr, deg, csr_src);
    k_agg1<<<(NN + 3) / 4, 256, 0, stream>>>(xlh2, xrh2, rowptr, deg, csr_src, att1, b1, hbh2);
    k_gemm2<<<(NN + 255) / 256, 256, 0, stream>>>(hbh2, W2l, W2r, xl2h, xr2h);
    k_agg2<<<(NN + 3) / 4, 256, 0, stream>>>(xl2h, xr2h, rowptr, deg, csr_src, att2, b2, out);
}

// Round 7
// 108.632 us; speedup vs baseline: 5.4118x; 1.1193x over previous
//
#include <hip/hip_runtime.h>
#include <math.h>

#define NN 50000
#define NE 800000
#define FIN 128
#define NC 10
#define NEG 0.2f

#define NB 196        // coarse buckets = ceil(NN/256), bucket = dst>>8
#define CHUNK 4096    // edges per pass1 block
#define P1B ((NE + CHUNK - 1) / CHUNK)   // 196
#define CAP 5120      // temp capacity per bucket
#define G1T ((NN + 127) / 128)           // 391 gemm1 tiles

typedef unsigned int uint;
typedef unsigned char uchar;
typedef _Float16 h2 __attribute__((ext_vector_type(2)));
typedef __fp16 hb2 __attribute__((ext_vector_type(2)));
union U2H { uint u; h2 h; };

// pack 2 floats -> half2 bits (builtin returns __fp16v2; go through a union)
__device__ __forceinline__ uint pkrtz_u(float a, float b) {
    union { hb2 f; uint u; } r;
    r.f = __builtin_amdgcn_cvt_pkrtz(a, b);
    return r.u;
}

__device__ __forceinline__ float dot2f(h2 a, h2 b, float c) {
#if __has_builtin(__builtin_amdgcn_fdot2)
    return __builtin_amdgcn_fdot2(a, b, c, false);
#else
    return fmaf((float)a.x, (float)b.x, fmaf((float)a.y, (float)b.y, c));
#endif
}

// packed leaky-relu: max(v, 0.2*v)
__device__ __forceinline__ h2 lrelu2(h2 v) {
    return __builtin_elementwise_max(v, v * (_Float16)0.2f);
}

template<int CTRL>
__device__ __forceinline__ float dpp_add(float x) {
    int y = __builtin_amdgcn_update_dpp(0, __float_as_int(x), CTRL, 0xF, 0xF, true);
    return x + __int_as_float(y);
}
// sum over aligned 8-lane groups (= one attention head's channels in half2 layout)
__device__ __forceinline__ float red8(float t) {
    t = dpp_add<0xB1>(t);
    t = dpp_add<0x4E>(t);
    t = dpp_add<0x141>(t);
    return t;
}

__device__ __forceinline__ int excl_scan256(int v, int* sc) {
    const int t = threadIdx.x;
    sc[t] = v;
    __syncthreads();
    for (int o = 1; o < 256; o <<= 1) {
        int u = (t >= o) ? sc[t - o] : 0;
        __syncthreads();
        sc[t] += u;
        __syncthreads();
    }
    return sc[t] - v;
}

// ---------------- tiny init (replaces pathological hipMemsetAsync blit) ----------------

__global__ void k_zinit(int* __restrict__ g) {
    if (threadIdx.x < NB) g[threadIdx.x] = 0;
}

// ---------------- fused kernel A: pass1 bucket-scatter || gemm1(f16) ----------------

__device__ void pass1_body(const int* __restrict__ ei, uint* __restrict__ temp,
                           int* __restrict__ gcursor, char* smraw) {
    uint*  pk = (uint*)smraw;                 // 16384 B [4096]
    uchar* bk = (uchar*)(smraw + 16384);      // 4096 B
    int* h  = (int*)(smraw + 20480);          // 1024
    int* h2_ = (int*)(smraw + 21504);         // 1024
    int* gb = (int*)(smraw + 22528);          // 1024
    int* lb = (int*)(smraw + 23552);          // 1024
    int* sc = (int*)(smraw + 24576);          // 1024
    const int t = threadIdx.x;
    const int e0 = blockIdx.x * CHUNK;
    const int cnt = min(CHUNK, NE - e0);

    h[t] = 0; h2_[t] = 0;
    __syncthreads();
    for (int i = t; i < cnt; i += 256) {
        int d = ei[NE + e0 + i];
        atomicAdd(&h[d >> 8], 1);
    }
    __syncthreads();
    const int hv = h[t];
    const int ex = excl_scan256(hv, sc);
    lb[t] = ex;
    if (t < NB && hv > 0) gb[t] = atomicAdd(&gcursor[t], hv);
    __syncthreads();
    for (int i = t; i < cnt; i += 256) {
        int s = ei[e0 + i];
        int d = ei[NE + e0 + i];
        int b = d >> 8;
        int r = atomicAdd(&h2_[b], 1);
        int pos = lb[b] + r;
        pk[pos] = ((uint)s << 8) | ((uint)d & 255u);
        bk[pos] = (uchar)b;
    }
    __syncthreads();
    for (int i = t; i < cnt; i += 256) {
        uint v = pk[i];
        int b = bk[i];
        int pos = gb[b] + (i - lb[b]);
        if (pos < CAP) temp[b * CAP + pos] = v;
    }
}

// xl/xr stored as half2 pairs: oh2[n*32 + pair]
__device__ void gemm1_body(const float* __restrict__ x, const float* __restrict__ W,
                           uint* __restrict__ oh2, int n0, char* smraw) {
    uint (*Wsh)[64]  = (uint(*)[64])smraw;             // [64 kp][64 col] 16KB
    uint (*xTh)[128] = (uint(*)[128])(smraw + 16384);  // [16 kp][128 node] 8KB
    const int t = threadIdx.x;

    for (int i = t; i < 4096; i += 256) {   // stage W as k-paired half2
        int kp = i >> 6, col = i & 63;
        Wsh[kp][col] = pkrtz_u(W[(2 * kp) * 64 + col], W[(2 * kp + 1) * 64 + col]);
    }

    const int tn = t >> 4;          // node group: nodes tn*8..+7
    const int tc = t & 15;          // col group : cols tc*4..+3
    float acc[8][4] = {};
    const int sn = t >> 1;          // staging node 0..127
    const int kp0 = (t & 1) * 8;    // staging k-pair offset within chunk

    for (int kc = 0; kc < FIN; kc += 32) {
        __syncthreads();
        {
            int gn = n0 + sn;
            float4 v0, v1, v2, v3;
            if (gn < NN) {
                const float4* xr_ = (const float4*)(x + (size_t)gn * FIN + kc + kp0 * 2);
                v0 = xr_[0]; v1 = xr_[1]; v2 = xr_[2]; v3 = xr_[3];
            } else {
                v0 = v1 = v2 = v3 = make_float4(0.f, 0.f, 0.f, 0.f);
            }
            xTh[kp0 + 0][sn] = pkrtz_u(v0.x, v0.y);
            xTh[kp0 + 1][sn] = pkrtz_u(v0.z, v0.w);
            xTh[kp0 + 2][sn] = pkrtz_u(v1.x, v1.y);
            xTh[kp0 + 3][sn] = pkrtz_u(v1.z, v1.w);
            xTh[kp0 + 4][sn] = pkrtz_u(v2.x, v2.y);
            xTh[kp0 + 5][sn] = pkrtz_u(v2.z, v2.w);
            xTh[kp0 + 6][sn] = pkrtz_u(v3.x, v3.y);
            xTh[kp0 + 7][sn] = pkrtz_u(v3.z, v3.w);
        }
        __syncthreads();
        const int kpc = kc >> 1;
#pragma unroll
        for (int kp = 0; kp < 16; ++kp) {
            uint4 wv = *(const uint4*)&Wsh[kpc + kp][tc * 4];
            uint4 xa = *(const uint4*)&xTh[kp][tn * 8];
            uint4 xb = *(const uint4*)&xTh[kp][tn * 8 + 4];
            U2H w0, w1, w2, w3, x0, x1, x2, x3, x4, x5, x6, x7;
            w0.u = wv.x; w1.u = wv.y; w2.u = wv.z; w3.u = wv.w;
            x0.u = xa.x; x1.u = xa.y; x2.u = xa.z; x3.u = xa.w;
            x4.u = xb.x; x5.u = xb.y; x6.u = xb.z; x7.u = xb.w;
            h2 xs[8] = {x0.h, x1.h, x2.h, x3.h, x4.h, x5.h, x6.h, x7.h};
#pragma unroll
            for (int i = 0; i < 8; ++i) {
                acc[i][0] = dot2f(xs[i], w0.h, acc[i][0]);
                acc[i][1] = dot2f(xs[i], w1.h, acc[i][1]);
                acc[i][2] = dot2f(xs[i], w2.h, acc[i][2]);
                acc[i][3] = dot2f(xs[i], w3.h, acc[i][3]);
            }
        }
    }
#pragma unroll
    for (int i = 0; i < 8; ++i) {
        int n = n0 + tn * 8 + i;
        if (n < NN) {
            uint p0 = pkrtz_u(acc[i][0], acc[i][1]);
            uint p1 = pkrtz_u(acc[i][2], acc[i][3]);
            *(uint2*)&oh2[(size_t)n * 32 + tc * 2] = make_uint2(p0, p1);
        }
    }
}

__global__ __launch_bounds__(256) void k_fusedA(const float* __restrict__ x,
                                                const int* __restrict__ ei,
                                                const float* __restrict__ W1l,
                                                const float* __restrict__ W1r,
                                                uint* __restrict__ xlh2,
                                                uint* __restrict__ xrh2,
                                                uint* __restrict__ temp,
                                                int* __restrict__ gcursor) {
    __shared__ __align__(16) char smraw[25600];
    if (blockIdx.x < P1B) {
        pass1_body(ei, temp, gcursor, smraw);
    } else {
        int g = blockIdx.x - P1B;
        bool left = g < G1T;
        int n0 = (left ? g : g - G1T) * 128;
        gemm1_body(x, left ? W1l : W1r, left ? xlh2 : xrh2, n0, smraw);
    }
}

// ---------------- pass2: per-bucket exact CSR ----------------

__global__ __launch_bounds__(256) void k_pass2(const uint* __restrict__ temp,
                                               const int* __restrict__ gcursor,
                                               int* __restrict__ rowptr,
                                               int* __restrict__ deg,
                                               int* __restrict__ csr_src) {
    __shared__ uint P[CAP];
    __shared__ int nh[256], nbx[256], ncur[256], sc[256];
    __shared__ int csrbase_s;
    const int t = threadIdx.x;
    const int b = blockIdx.x;

    int gc = (t < NB) ? gcursor[t] : 0;
    int base_ex = excl_scan256(gc, sc);
    if (t == b) csrbase_s = base_ex;
    nh[t] = 0; ncur[t] = 0;
    __syncthreads();
    const int csrbase = csrbase_s;
    const int cnt = min(gcursor[b], CAP);

    for (int i = t; i < cnt; i += 256) {
        uint v = temp[b * CAP + i];
        P[i] = v;
        atomicAdd(&nh[v & 255u], 1);
    }
    __syncthreads();
    const int c = nh[t];
    const int nb_ex = excl_scan256(c, sc);
    nbx[t] = nb_ex;
    const int gnode = b * 256 + t;
    if (gnode < NN) { rowptr[gnode] = csrbase + nb_ex; deg[gnode] = c; }
    __syncthreads();
    for (int i = t; i < cnt; i += 256) {
        uint v = P[i];
        int l = (int)(v & 255u);
        int r = atomicAdd(&ncur[l], 1);
        csr_src[csrbase + nbx[l] + r] = (int)(v >> 8);
    }
}

// ---------------- layer 1 aggregate: 4-edge pipelined, half2 lanes ----------------

__global__ __launch_bounds__(256) void k_agg1(const uint* __restrict__ xlh2,
                                              const uint* __restrict__ xrh2,
                                              const int* __restrict__ rowptr,
                                              const int* __restrict__ deg,
                                              const int* __restrict__ csr_src,
                                              const float* __restrict__ att1,
                                              const float* __restrict__ b1,
                                              uint* __restrict__ hbh2) {
    const int node = blockIdx.x * 4 + (threadIdx.x >> 6);
    if (node >= NN) return;
    const int lane = threadIdx.x & 63;
    const int fl = lane & 31;        // feature-pair
    const int hid = lane >> 5;       // edge-half id
    float2 av = *(const float2*)&att1[2 * fl];
    U2H att; att.u = pkrtz_u(av.x, av.y);
    U2H xrf; xrf.u = xrh2[(size_t)node * 32 + fl];
    const int start = rowptr[node];
    const int dg = deg[node];
    const int permbase = (lane & 32) >> 3;   // 0 or 4

    float denom = 0.f, acc0 = 0.f, acc1 = 0.f;
    for (int base = 0; base < dg; base += 64) {
        int idx = base + lane;
        int srcs = (idx < dg) ? csr_src[start + idx] : 0;
        int rem = dg - base; if (rem > 64) rem = 64;
        int iters = (rem + 1) >> 1;
        int thr = (rem - hid + 1) >> 1;      // edge (2j+hid) valid iff j < thr
        int jj = 0;
        for (; jj + 4 <= iters; jj += 4) {
            int s0 = __builtin_amdgcn_ds_bpermute(jj * 8 +  0 + permbase, srcs);
            int s1 = __builtin_amdgcn_ds_bpermute(jj * 8 +  8 + permbase, srcs);
            int s2 = __builtin_amdgcn_ds_bpermute(jj * 8 + 16 + permbase, srcs);
            int s3 = __builtin_amdgcn_ds_bpermute(jj * 8 + 24 + permbase, srcs);
            U2H v0; v0.u = xlh2[(size_t)s0 * 32 + fl];
            U2H v1; v1.u = xlh2[(size_t)s1 * 32 + fl];
            U2H v2; v2.u = xlh2[(size_t)s2 * 32 + fl];
            U2H v3; v3.u = xlh2[(size_t)s3 * 32 + fl];
            float t0 = red8(dot2f(lrelu2(v0.h + xrf.h), att.h, 0.f));
            float t1 = red8(dot2f(lrelu2(v1.h + xrf.h), att.h, 0.f));
            float t2 = red8(dot2f(lrelu2(v2.h + xrf.h), att.h, 0.f));
            float t3 = red8(dot2f(lrelu2(v3.h + xrf.h), att.h, 0.f));
            float e0 = (jj + 0 < thr) ? __expf(t0) : 0.f;
            float e1 = (jj + 1 < thr) ? __expf(t1) : 0.f;
            float e2 = (jj + 2 < thr) ? __expf(t2) : 0.f;
            float e3 = (jj + 3 < thr) ? __expf(t3) : 0.f;
            denom += (e0 + e1) + (e2 + e3);
            acc0 = fmaf(e0, (float)v0.h.x, acc0);
            acc0 = fmaf(e1, (float)v1.h.x, acc0);
            acc0 = fmaf(e2, (float)v2.h.x, acc0);
            acc0 = fmaf(e3, (float)v3.h.x, acc0);
            acc1 = fmaf(e0, (float)v0.h.y, acc1);
            acc1 = fmaf(e1, (float)v1.h.y, acc1);
            acc1 = fmaf(e2, (float)v2.h.y, acc1);
            acc1 = fmaf(e3, (float)v3.h.y, acc1);
        }
        for (; jj < iters; ++jj) {
            int s0 = __builtin_amdgcn_ds_bpermute(jj * 8 + permbase, srcs);
            U2H v0; v0.u = xlh2[(size_t)s0 * 32 + fl];
            float t0 = red8(dot2f(lrelu2(v0.h + xrf.h), att.h, 0.f));
            float e0 = (jj < thr) ? __expf(t0) : 0.f;
            denom += e0;
            acc0 = fmaf(e0, (float)v0.h.x, acc0);
            acc1 = fmaf(e0, (float)v0.h.y, acc1);
        }
    }
    denom += __shfl_xor(denom, 32);
    acc0  += __shfl_xor(acc0, 32);
    acc1  += __shfl_xor(acc1, 32);
    if (lane < 32) {
        float r = (dg > 0) ? (1.0f / denom) : 0.f;
        float2 bv = *(const float2*)&b1[2 * fl];
        float o0 = fmaf(acc0, r, bv.x);
        float o1 = fmaf(acc1, r, bv.y);
        o0 = o0 > 0.f ? o0 : expm1f(o0);
        o1 = o1 > 0.f ? o1 : expm1f(o1);
        hbh2[(size_t)node * 32 + fl] = pkrtz_u(o0, o1);
    }
}

// ---------------- layer 2 GEMM: node per thread, packed half2 outputs ----------------

__global__ __launch_bounds__(256) void k_gemm2(const uint* __restrict__ hbh2,
                                               const float* __restrict__ W2l,
                                               const float* __restrict__ W2r,
                                               uint* __restrict__ xl2h,
                                               uint* __restrict__ xr2h) {
    int n = blockIdx.x * 256 + threadIdx.x;
    if (n >= NN) return;
    float al[NC] = {}, ar[NC] = {};
    const uint4* hr4 = (const uint4*)(hbh2 + (size_t)n * 32);
#pragma unroll
    for (int q = 0; q < 8; ++q) {
        uint4 qq = hr4[q];
        uint uu[4] = {qq.x, qq.y, qq.z, qq.w};
#pragma unroll
        for (int j = 0; j < 4; ++j) {
            U2H hh; hh.u = uu[j];
            float f0 = (float)hh.h.x, f1 = (float)hh.h.y;
            int k = q * 8 + j * 2;
            const float* wl0 = W2l + k * NC;
            const float* wr0 = W2r + k * NC;
#pragma unroll
            for (int c = 0; c < NC; ++c) {
                al[c] = fmaf(f0, wl0[c], fmaf(f1, wl0[NC + c], al[c]));
                ar[c] = fmaf(f0, wr0[c], fmaf(f1, wr0[NC + c], ar[c]));
            }
        }
    }
    uint p0 = pkrtz_u(al[0], al[1]);
    uint p1 = pkrtz_u(al[2], al[3]);
    uint p2 = pkrtz_u(al[4], al[5]);
    uint p3 = pkrtz_u(al[6], al[7]);
    uint p4 = pkrtz_u(al[8], al[9]);
    *(uint4*)&xl2h[(size_t)n * 8]     = make_uint4(p0, p1, p2, p3);
    *(uint4*)&xl2h[(size_t)n * 8 + 4] = make_uint4(p4, 0u, 0u, 0u);
    p0 = pkrtz_u(ar[0], ar[1]);
    p1 = pkrtz_u(ar[2], ar[3]);
    p2 = pkrtz_u(ar[4], ar[5]);
    p3 = pkrtz_u(ar[6], ar[7]);
    p4 = pkrtz_u(ar[8], ar[9]);
    *(uint4*)&xr2h[(size_t)n * 8]     = make_uint4(p0, p1, p2, p3);
    *(uint4*)&xr2h[(size_t)n * 8 + 4] = make_uint4(p4, 0u, 0u, 0u);
}

// ---------------- layer 2 aggregate: 16 edges in flight per wave ----------------

__global__ __launch_bounds__(256) void k_agg2(const uint* __restrict__ xl2h,
                                              const uint* __restrict__ xr2h,
                                              const int* __restrict__ rowptr,
                                              const int* __restrict__ deg,
                                              const int* __restrict__ csr_src,
                                              const float* __restrict__ att2,
                                              const float* __restrict__ b2,
                                              float* __restrict__ out) {
    const int node = blockIdx.x * 4 + (threadIdx.x >> 6);
    if (node >= NN) return;
    const int lane = threadIdx.x & 63;
    const int fp = lane & 7;         // feature-pair (0..4 real, 5..7 pad)
    const int eg = lane >> 3;        // edge group 0..7
    U2H att;
    if (fp < 5) {
        float2 av = *(const float2*)&att2[2 * fp];
        att.u = pkrtz_u(av.x, av.y);
    } else {
        att.u = 0;
    }
    U2H xrf; xrf.u = xr2h[(size_t)node * 8 + fp];
    const int start = rowptr[node];
    const int dg = deg[node];
    const int permbase = eg * 4;

    float denom = 0.f, acc0 = 0.f, acc1 = 0.f;
    for (int base = 0; base < dg; base += 64) {
        int idx = base + lane;
        int srcs = (idx < dg) ? csr_src[start + idx] : 0;
        int rem = dg - base; if (rem > 64) rem = 64;
        int iters = (rem + 7) >> 3;
        int thr = (rem - eg + 7) >> 3;       // edge (8j+eg) valid iff j < thr
        int jj = 0;
        for (; jj + 2 <= iters; jj += 2) {
            int s0 = __builtin_amdgcn_ds_bpermute(jj * 32 + permbase, srcs);
            int s1 = __builtin_amdgcn_ds_bpermute(jj * 32 + 32 + permbase, srcs);
            U2H v0; v0.u = xl2h[(size_t)s0 * 8 + fp];
            U2H v1; v1.u = xl2h[(size_t)s1 * 8 + fp];
            float t0 = red8(dot2f(lrelu2(v0.h + xrf.h), att.h, 0.f));
            float t1 = red8(dot2f(lrelu2(v1.h + xrf.h), att.h, 0.f));
            float e0 = (jj + 0 < thr) ? __expf(t0) : 0.f;
            float e1 = (jj + 1 < thr) ? __expf(t1) : 0.f;
            denom += e0 + e1;
            acc0 = fmaf(e0, (float)v0.h.x, acc0);
            acc0 = fmaf(e1, (float)v1.h.x, acc0);
            acc1 = fmaf(e0, (float)v0.h.y, acc1);
            acc1 = fmaf(e1, (float)v1.h.y, acc1);
        }
        if (jj < iters) {
            int s0 = __builtin_amdgcn_ds_bpermute(jj * 32 + permbase, srcs);
            U2H v0; v0.u = xl2h[(size_t)s0 * 8 + fp];
            float t0 = red8(dot2f(lrelu2(v0.h + xrf.h), att.h, 0.f));
            float e0 = (jj < thr) ? __expf(t0) : 0.f;
            denom += e0;
            acc0 = fmaf(e0, (float)v0.h.x, acc0);
            acc1 = fmaf(e0, (float)v0.h.y, acc1);
        }
    }
#pragma unroll
    for (int m = 8; m <= 32; m <<= 1) {
        denom += __shfl_xor(denom, m);
        acc0  += __shfl_xor(acc0, m);
        acc1  += __shfl_xor(acc1, m);
    }
    if (lane < 5) {   // eg==0, fp<5
        float r = (dg > 0) ? (1.0f / denom) : 0.f;
        float2 o;
        o.x = fmaf(acc0, r, b2[2 * fp]);
        o.y = fmaf(acc1, r, b2[2 * fp + 1]);
        *(float2*)&out[(size_t)node * NC + 2 * fp] = o;
    }
}

// ---------------- launch ----------------

extern "C" void kernel_launch(void* const* d_in, const int* in_sizes, int n_in,
                              void* d_out, int out_size, void* d_ws, size_t ws_size,
                              hipStream_t stream) {
    const float* x    = (const float*)d_in[0];
    const int*   ei   = (const int*)d_in[1];
    const float* W1l  = (const float*)d_in[2];
    const float* W1r  = (const float*)d_in[3];
    const float* att1 = (const float*)d_in[4];
    const float* b1   = (const float*)d_in[5];
    const float* W2l  = (const float*)d_in[6];
    const float* W2r  = (const float*)d_in[7];
    const float* att2 = (const float*)d_in[8];
    const float* b2   = (const float*)d_in[9];
    float* out = (float*)d_out;

    char* w = (char*)d_ws;
    size_t off = 0;
    auto alloc = [&](size_t bytes) -> void* {
        void* p = w + off;
        off = (off + bytes + 255) & ~(size_t)255;
        return p;
    };
    uint* xlh2   = (uint*)alloc((size_t)NN * 32 * 4);
    uint* xrh2   = (uint*)alloc((size_t)NN * 32 * 4);
    uint* hbh2   = (uint*)alloc((size_t)NN * 32 * 4);
    uint* xl2h   = (uint*)alloc((size_t)NN * 8 * 4);
    uint* xr2h   = (uint*)alloc((size_t)NN * 8 * 4);
    uint* temp   = (uint*)alloc((size_t)NB * CAP * 4);
    int*  gcursor = (int*)alloc((size_t)NB * 4);
    int*  rowptr  = (int*)alloc((size_t)NN * 4);
    int*  deg     = (int*)alloc((size_t)NN * 4);
    int*  csr_src = (int*)alloc((size_t)NE * 4);

    k_zinit<<<1, 256, 0, stream>>>(gcursor);
    k_fusedA<<<P1B + 2 * G1T, 256, 0, stream>>>(x, ei, W1l, W1r, xlh2, xrh2, temp, gcursor);
    k_pass2<<<NB, 256, 0, stream>>>(temp, gcursor, rowptr, deg, csr_src);
    k_agg1<<<(NN + 3) / 4, 256, 0, stream>>>(xlh2, xrh2, rowptr, deg, csr_src, att1, b1, hbh2);
    k_gemm2<<<(NN + 255) / 256, 256, 0, stream>>>(hbh2, W2l, W2r, xl2h, xr2h);
    k_agg2<<<(NN + 3) / 4, 256, 0, stream>>>(xl2h, xr2h, rowptr, deg, csr_src, att2, b2, out);
}